// Round 1
// baseline (837.685 us; speedup 1.0000x reference)
//
#include <hip/hip_runtime.h>
#include <hip/hip_bf16.h>
#include <stdint.h>

#define N_NODES 30000
#define M_PAD   30080      // 235 * 128, GEMM M padding
#define N_EDGES 480000
#define F_IN 376
#define K1   384           // F_IN padded to BK multiple
#define HID 512
#define DENSE_F 1536
#define NHEADS 20          // 4 (gat1) + 16 (gat2)
#define HG_LD 32           // hgat leading dim (fp32): 3.85 MB, L2-resident

typedef __bf16 bf16_t;
typedef bf16_t bf16x8 __attribute__((ext_vector_type(8)));
typedef float  f32x4  __attribute__((ext_vector_type(4)));

#define S1 (512 * K1)
#define S2 (512 * 512)
#define S3 (512 * 1024)
#define S4 (128 * DENSE_F)
#define PW_ELEMS (S1 + S2 + S3 + S4 + NHEADS)

#define EB_BLOCKS ((N_EDGES + 255) / 256)
#define CX_BLOCKS ((M_PAD * K1) / 256)           // 45120 exactly
#define PW_BLOCKS ((PW_ELEMS + 255) / 256)
#define PRO_BLOCKS (EB_BLOCKS + CX_BLOCKS + PW_BLOCKS)

// ---------------------------------------------------------------------------
// Fused prologue: three independent stages run concurrently in one launch.
//   [0, EB)           build_stats : deg/cnt atomics over edges
//   [EB, EB+CX)       conv_x      : x fp32 -> x_bf bf16 padded
//   [EB+CX, ...)      pack_weights: all weight transposes/padding
// ---------------------------------------------------------------------------
__global__ __launch_bounds__(256) void prologue(
    const int* __restrict__ dst, const float* __restrict__ ew,
    float* __restrict__ deg, int* __restrict__ cnt,
    const float* __restrict__ x, bf16_t* __restrict__ xb,
    const float* __restrict__ W1, const float* __restrict__ W2,
    const float* __restrict__ Wl, const float* __restrict__ Wr,
    const float* __restrict__ g1W, const float* __restrict__ g2W,
    const float* __restrict__ a1s, const float* __restrict__ a1d,
    const float* __restrict__ a2s, const float* __restrict__ a2d,
    bf16_t* __restrict__ W1t, bf16_t* __restrict__ W2t,
    bf16_t* __restrict__ Bst, bf16_t* __restrict__ Wgt,
    float* __restrict__ asrc, float* __restrict__ adst)
{
    int b = blockIdx.x;
    if (b < EB_BLOCKS) {
        int e = b * 256 + threadIdx.x;
        if (e >= N_EDGES) return;
        int t = dst[e];
        atomicAdd(&deg[t], ew[e]);
        atomicAdd(&cnt[t], 1);
    } else if (b < EB_BLOCKS + CX_BLOCKS) {
        int tid = (b - EB_BLOCKS) * 256 + threadIdx.x;
        int r = tid / K1, c = tid - r * K1;
        float v = (r < N_NODES && c < F_IN) ? x[r * F_IN + c] : 0.f;
        xb[tid] = (bf16_t)v;
    } else {
        int tid = (b - EB_BLOCKS - CX_BLOCKS) * 256 + threadIdx.x;
        if (tid < S1) {
            int n = tid / K1, k = tid - n * K1;
            W1t[tid] = (bf16_t)((k < F_IN) ? W1[k * HID + n] : 0.f);
        } else if (tid < S1 + S2) {
            int t = tid - S1;
            int n = t >> 9, k = t & 511;
            W2t[t] = (bf16_t)W2[k * HID + n];
        } else if (tid < S1 + S2 + S3) {
            int t = tid - S1 - S2;
            int n = t >> 10, k = t & 1023;
            Bst[t] = (bf16_t)((k < HID) ? Wl[k * HID + n] : Wr[(k - HID) * HID + n]);
        } else if (tid < S1 + S2 + S3 + S4) {
            int t = tid - S1 - S2 - S3;
            int n = t / DENSE_F, k = t - n * DENSE_F;
            float v = (n < 4) ? g1W[k * 4 + n] : (n < NHEADS) ? g2W[k * 16 + (n - 4)] : 0.f;
            Wgt[t] = (bf16_t)v;
        } else if (tid < S1 + S2 + S3 + S4 + NHEADS) {
            int hh = tid - S1 - S2 - S3 - S4;
            asrc[hh] = (hh < 4) ? a1s[hh] : a2s[hh - 4];
            adst[hh] = (hh < 4) ? a1d[hh] : a2d[hh - 4];
        }
    }
}

// ---------------------------------------------------------------------------
// Fast exclusive scan of cnt -> rowptr/woff, + node_stats fold (deg+1, rsqrt).
// 1 block, 1024 threads, each thread owns SEG=30 contiguous elements.
// Replaces 660-barrier Hillis-Steele with 2 barriers + shfl scans.
// ---------------------------------------------------------------------------
#define SEG 30
__global__ __launch_bounds__(1024) void scan_rowptr_fast(
    const int* __restrict__ cnt, int* __restrict__ rowptr, int* __restrict__ woff,
    float* __restrict__ deg, float* __restrict__ dinv)
{
    int t = threadIdx.x;
    int base = t * SEG;
    int v[SEG];
    int sum = 0;
#pragma unroll
    for (int j = 0; j < SEG; ++j) {
        int i = base + j;
        int c = (i < N_NODES) ? cnt[i] : 0;
        v[j] = c;
        sum += c;
        if (i < N_NODES) {
            float d = deg[i] + 1.0f;   // self-loop weight 1
            deg[i] = d;
            dinv[i] = rsqrtf(d);
        }
    }
    // wave-level inclusive scan of per-thread sums
    int lane = t & 63;
    int wid = t >> 6;
    int s = sum;
#pragma unroll
    for (int off = 1; off < 64; off <<= 1) {
        int u = __shfl_up(s, off);
        if (lane >= off) s += u;
    }
    __shared__ int wsum[16];
    if (lane == 63) wsum[wid] = s;
    __syncthreads();
    if (t < 16) {
        int ws = wsum[t];
#pragma unroll
        for (int off = 1; off < 16; off <<= 1) {
            int u = __shfl_up(ws, off);
            if (t >= off) ws += u;
        }
        wsum[t] = ws;
    }
    __syncthreads();
    int carry = (wid > 0) ? wsum[wid - 1] : 0;
    int excl = carry + s - sum;   // exclusive prefix for this thread's segment
#pragma unroll
    for (int j = 0; j < SEG; ++j) {
        int i = base + j;
        if (i < N_NODES) { rowptr[i] = excl; woff[i] = excl; }
        excl += v[j];
    }
    if (t == 1023) rowptr[N_NODES] = excl;   // total edge count
}

__global__ __launch_bounds__(256) void scatter_csr(
    const int* __restrict__ src, const int* __restrict__ dst,
    const float* __restrict__ ew, int* __restrict__ woff,
    int* __restrict__ col, float* __restrict__ wcsr)
{
    int e = blockIdx.x * 256 + threadIdx.x;
    if (e >= N_EDGES) return;
    int t = dst[e];
    int p = atomicAdd(&woff[t], 1);
    col[p] = src[e];
    wcsr[p] = ew[e];
}

// ---------------------------------------------------------------------------
// bf16 MFMA GEMM (NT) with fused epilogue and optional split-K accumulation:
//   acc = A * Bt^T  (fp32) over k in [kz*K/gridDim.z, (kz+1)*K/gridDim.z)
//   if bias: v = relu(acc + bias[col]) else v = acc
//   if C : accum ? atomicAdd(C[...], v) : C[...] = v   (fp32)
//   if Cb: Cb[...] = v  (bf16)
// 128x128 tile, BK=32, 4 waves, 16x16x32 MFMA, global_load_lds staging.
// ---------------------------------------------------------------------------
__global__ __launch_bounds__(256) void gemm_bf16(
    const bf16_t* __restrict__ A1, int lda1, int ksplit,
    const bf16_t* __restrict__ A2, int lda2,
    const bf16_t* __restrict__ Bt, int ldb,
    float* __restrict__ C, bf16_t* __restrict__ Cb, long ldc, int K,
    const float* __restrict__ bias, int ncols, int accum)
{
    __shared__ bf16_t As[128 * 32];
    __shared__ bf16_t Bs[128 * 32];
    const int tid = threadIdx.x;
    const int wid = tid >> 6, lane = tid & 63;
    const int li = lane & 15, kq = lane >> 4;
    const int wm = (wid >> 1) * 64, wn = (wid & 1) * 64;
    const long r0 = (long)blockIdx.y * 128;
    const int  n0 = blockIdx.x * 128;

    const int kb = K / (int)gridDim.z;
    const int k_lo = (int)blockIdx.z * kb;
    const int k_hi = k_lo + kb;

    f32x4 acc[4][4] = {};

    const int s0 = wid * 64 + lane;
    const int s1 = 256 + s0;
    const int am0 = s0 >> 2, ak0 = (s0 & 3) ^ ((am0 >> 1) & 3);
    const int am1 = s1 >> 2, ak1 = (s1 & 3) ^ ((am1 >> 1) & 3);
    const int swz = (li >> 1) & 3;

    for (int k0 = k_lo; k0 < k_hi; k0 += 32) {
        const bf16_t* Ab; int lda;
        if (k0 < ksplit) { Ab = A1 + k0;            lda = lda1; }
        else             { Ab = A2 + (k0 - ksplit); lda = lda2; }
        __builtin_amdgcn_global_load_lds(
            (const __attribute__((address_space(1))) void*)(Ab + (r0 + am0) * (long)lda + ak0 * 8),
            (__attribute__((address_space(3))) void*)(As + (wid * 64) * 8), 16, 0, 0);
        __builtin_amdgcn_global_load_lds(
            (const __attribute__((address_space(1))) void*)(Ab + (r0 + am1) * (long)lda + ak1 * 8),
            (__attribute__((address_space(3))) void*)(As + (256 + wid * 64) * 8), 16, 0, 0);
        __builtin_amdgcn_global_load_lds(
            (const __attribute__((address_space(1))) void*)(Bt + (n0 + am0) * (long)ldb + k0 + ak0 * 8),
            (__attribute__((address_space(3))) void*)(Bs + (wid * 64) * 8), 16, 0, 0);
        __builtin_amdgcn_global_load_lds(
            (const __attribute__((address_space(1))) void*)(Bt + (n0 + am1) * (long)ldb + k0 + ak1 * 8),
            (__attribute__((address_space(3))) void*)(Bs + (256 + wid * 64) * 8), 16, 0, 0);
        __syncthreads();

        bf16x8 a[4], b[4];
#pragma unroll
        for (int f = 0; f < 4; ++f) {
            int m = wm + f * 16 + li;
            a[f] = *(const bf16x8*)(As + m * 32 + ((kq ^ swz) * 8));
            int n = wn + f * 16 + li;
            b[f] = *(const bf16x8*)(Bs + n * 32 + ((kq ^ swz) * 8));
        }
#pragma unroll
        for (int fm = 0; fm < 4; ++fm)
#pragma unroll
            for (int fn = 0; fn < 4; ++fn)
                acc[fm][fn] = __builtin_amdgcn_mfma_f32_16x16x32_bf16(
                    a[fm], b[fn], acc[fm][fn], 0, 0, 0);
        __syncthreads();
    }

    // C/D layout: col = lane&15, row = (lane>>4)*4 + reg
#pragma unroll
    for (int fm = 0; fm < 4; ++fm) {
#pragma unroll
        for (int r = 0; r < 4; ++r) {
            long row = r0 + wm + fm * 16 + kq * 4 + r;
            if (row >= N_NODES) continue;
#pragma unroll
            for (int fn = 0; fn < 4; ++fn) {
                int colg = n0 + wn + fn * 16 + li;
                if (colg >= ncols) continue;
                float v = acc[fm][fn][r];
                if (bias) v = fmaxf(v + bias[colg], 0.f);
                if (C) {
                    if (accum) atomicAdd(&C[row * ldc + colg], v);
                    else       C[row * ldc + colg] = v;
                }
                if (Cb) Cb[row * ldc + colg] = (bf16_t)v;
            }
        }
    }
}

// ---------------------------------------------------------------------------
// GCN aggregation over raw x_bf (384 cols): aggx[i] = x[i]/deg + sum norm*x[s]
// 4 nodes per 256-thread block (one wave each) for higher resident-wave count.
// ---------------------------------------------------------------------------
__global__ __launch_bounds__(256) void agg_x(
    const bf16_t* __restrict__ xb, const int* __restrict__ rowptr,
    const int* __restrict__ col, const float* __restrict__ wcsr,
    const float* __restrict__ dinv, const float* __restrict__ deg,
    bf16_t* __restrict__ aggx)
{
    int i = blockIdx.x * 4 + (threadIdx.x >> 6);
    int lane = threadIdx.x & 63;
    int c = lane * 8;
    bool act = (c < K1);
    float di = dinv[i];
    float selfw = 1.0f / deg[i];
    float acc0[8] = {}, acc1[8] = {};
    if (act) {
        bf16x8 sv = *(const bf16x8*)(xb + (long)i * K1 + c);
#pragma unroll
        for (int j = 0; j < 8; ++j) acc0[j] = selfw * (float)sv[j];
    }
    int e = rowptr[i], e1 = rowptr[i + 1];
    for (; e + 1 < e1; e += 2) {
        int sA = col[e], sB = col[e + 1];
        float wA = dinv[sA] * wcsr[e] * di;
        float wB = dinv[sB] * wcsr[e + 1] * di;
        if (act) {
            bf16x8 vA = *(const bf16x8*)(xb + (long)sA * K1 + c);
            bf16x8 vB = *(const bf16x8*)(xb + (long)sB * K1 + c);
#pragma unroll
            for (int j = 0; j < 8; ++j) {
                acc0[j] = fmaf(wA, (float)vA[j], acc0[j]);
                acc1[j] = fmaf(wB, (float)vB[j], acc1[j]);
            }
        }
    }
    if (e < e1) {
        int sA = col[e];
        float wA = dinv[sA] * wcsr[e] * di;
        if (act) {
            bf16x8 vA = *(const bf16x8*)(xb + (long)sA * K1 + c);
#pragma unroll
            for (int j = 0; j < 8; ++j) acc0[j] = fmaf(wA, (float)vA[j], acc0[j]);
        }
    }
    if (act) {
        bf16x8 ob;
#pragma unroll
        for (int j = 0; j < 8; ++j) ob[j] = (bf16_t)(acc0[j] + acc1[j]);
        *reinterpret_cast<bf16x8*>(aggx + (long)i * K1 + c) = ob;
    }
}

// ---------------------------------------------------------------------------
// Fused x1 aggregation: ONE gather of x1 rows serves GCN2 (norm-weighted sum
// + self) AND SAGE (plain mean). 4 nodes per block, lane owns 8 of 512 cols.
// ---------------------------------------------------------------------------
__global__ __launch_bounds__(256) void agg_x1(
    const bf16_t* __restrict__ x1b /* dense_bf, cols [0,512) */,
    const int* __restrict__ rowptr, const int* __restrict__ col,
    const float* __restrict__ wcsr, const float* __restrict__ dinv,
    const float* __restrict__ deg, const int* __restrict__ cnt,
    bf16_t* __restrict__ gbf, bf16_t* __restrict__ meanb)
{
    int i = blockIdx.x * 4 + (threadIdx.x >> 6);
    int lane = threadIdx.x & 63;
    int c = lane * 8;
    float di = dinv[i];
    float selfw = 1.0f / deg[i];
    bf16x8 sv = *(const bf16x8*)(x1b + (long)i * DENSE_F + c);
    float g0[8], g1[8], m0[8], m1[8];
#pragma unroll
    for (int j = 0; j < 8; ++j) {
        g0[j] = selfw * (float)sv[j];
        g1[j] = 0.f; m0[j] = 0.f; m1[j] = 0.f;
    }
    int e = rowptr[i], e1 = rowptr[i + 1];
    for (; e + 1 < e1; e += 2) {
        int sA = col[e], sB = col[e + 1];
        float wA = dinv[sA] * wcsr[e] * di;
        float wB = dinv[sB] * wcsr[e + 1] * di;
        bf16x8 vA = *(const bf16x8*)(x1b + (long)sA * DENSE_F + c);
        bf16x8 vB = *(const bf16x8*)(x1b + (long)sB * DENSE_F + c);
#pragma unroll
        for (int j = 0; j < 8; ++j) {
            float fA = (float)vA[j], fB = (float)vB[j];
            g0[j] = fmaf(wA, fA, g0[j]);
            g1[j] = fmaf(wB, fB, g1[j]);
            m0[j] += fA;
            m1[j] += fB;
        }
    }
    if (e < e1) {
        int sA = col[e];
        float wA = dinv[sA] * wcsr[e] * di;
        bf16x8 vA = *(const bf16x8*)(x1b + (long)sA * DENSE_F + c);
#pragma unroll
        for (int j = 0; j < 8; ++j) {
            float fA = (float)vA[j];
            g0[j] = fmaf(wA, fA, g0[j]);
            m0[j] += fA;
        }
    }
    float inv = 1.0f / fmaxf((float)cnt[i], 1.0f);
    bf16x8 og, om;
#pragma unroll
    for (int j = 0; j < 8; ++j) {
        og[j] = (bf16_t)(g0[j] + g1[j]);
        om[j] = (bf16_t)((m0[j] + m1[j]) * inv);
    }
    *reinterpret_cast<bf16x8*>(gbf   + (long)i * HID + c) = og;
    *reinterpret_cast<bf16x8*>(meanb + (long)i * HID + c) = om;
}

// per-dst GAT attention over CSR (+self loop), softmax shift-free,
// hgat stride HG_LD=32 (3.85 MB, L2-resident), 2-edge unroll.
// 4 nodes per 256-thread block (one wave each).
__global__ __launch_bounds__(256) void gat_agg(
    const float* __restrict__ hgat, const int* __restrict__ rowptr,
    const int* __restrict__ col, const float* __restrict__ asrc,
    const float* __restrict__ adst, const float* __restrict__ b1p,
    const float* __restrict__ b2p, float* __restrict__ xout)
{
    int i = blockIdx.x * 4 + (threadIdx.x >> 6);
    int lane = threadIdx.x & 63;
    int h = (lane < NHEADS) ? lane : 0;
    float hg_i = hgat[(long)i * HG_LD + h];
    float as = asrc[h], ad = adst[h];
    float adhg = ad * hg_i;
    float ev = hg_i * as + adhg;
    ev = ev > 0.f ? ev : 0.2f * ev;
    float ex = __expf(ev);
    float den0 = ex, og0 = ex * hg_i, den1 = 0.f, og1 = 0.f;
    int e = rowptr[i], e1 = rowptr[i + 1];
    for (; e + 1 < e1; e += 2) {
        int sA = col[e], sB = col[e + 1];
        float hA = hgat[(long)sA * HG_LD + h];
        float hB = hgat[(long)sB * HG_LD + h];
        float tA = fmaf(hA, as, adhg); tA = tA > 0.f ? tA : 0.2f * tA;
        float tB = fmaf(hB, as, adhg); tB = tB > 0.f ? tB : 0.2f * tB;
        float xA = __expf(tA), xB = __expf(tB);
        den0 += xA; og0 = fmaf(xA, hA, og0);
        den1 += xB; og1 = fmaf(xB, hB, og1);
    }
    if (e < e1) {
        int sA = col[e];
        float hA = hgat[(long)sA * HG_LD + h];
        float tA = fmaf(hA, as, adhg); tA = tA > 0.f ? tA : 0.2f * tA;
        float xA = __expf(tA);
        den0 += xA; og0 = fmaf(xA, hA, og0);
    }
    float out = (lane < NHEADS) ? (og0 + og1) / (den0 + den1) : 0.f;
    float s4 = out + __shfl_xor(out, 1);
    s4 += __shfl_xor(s4, 2);
    float g0 = __shfl(s4, 0);
    float g1 = __shfl(s4, 4);
    float g2 = __shfl(s4, 8);
    float g3 = __shfl(s4, 12);
    float g4 = __shfl(s4, 16);
    if (lane == 0) {
        float a1 = g0 * 0.25f + b1p[0];
        float a2 = (g1 + g2 + g3 + g4) * 0.0625f + b2p[0];
        xout[i] = 0.5f * (a1 + a2);
    }
}

// ---------------------------------------------------------------------------
extern "C" void kernel_launch(void* const* d_in, const int* in_sizes, int n_in,
                              void* d_out, int out_size, void* d_ws, size_t ws_size,
                              hipStream_t stream) {
    (void)in_sizes; (void)n_in; (void)out_size; (void)ws_size;
    const float* x    = (const float*)d_in[0];
    const int*   ei   = (const int*)d_in[1];
    const float* ew   = (const float*)d_in[2];
    const float* W1   = (const float*)d_in[3];
    const float* b1   = (const float*)d_in[4];
    const float* W2   = (const float*)d_in[5];
    const float* b2   = (const float*)d_in[6];
    const float* sWl  = (const float*)d_in[7];
    const float* sWr  = (const float*)d_in[8];
    const float* sb   = (const float*)d_in[9];
    const float* g1W  = (const float*)d_in[10];
    const float* g1as = (const float*)d_in[11];
    const float* g1ad = (const float*)d_in[12];
    const float* g1b  = (const float*)d_in[13];
    const float* g2W  = (const float*)d_in[14];
    const float* g2as = (const float*)d_in[15];
    const float* g2ad = (const float*)d_in[16];
    const float* g2b  = (const float*)d_in[17];

    const int* src = ei;
    const int* dst = ei + N_EDGES;

    float* xout  = (float*)d_out;          // [N]
    float* dense = xout + N_NODES;         // [N,1536] fp32 (output 2)

    size_t off = 0;
    auto alloc = [&](size_t nbytes) -> void* {
        void* p = (char*)d_ws + off;
        off += (nbytes + 255) & ~(size_t)255;
        return p;
    };
    bf16_t* dense_bf = (bf16_t*)alloc((size_t)M_PAD * DENSE_F * 2);
    bf16_t* x_bf     = (bf16_t*)alloc((size_t)M_PAD * K1 * 2);
    bf16_t* aggx_bf  = (bf16_t*)alloc((size_t)M_PAD * K1 * 2);
    bf16_t* g_bf     = (bf16_t*)alloc((size_t)M_PAD * HID * 2);
    bf16_t* mean_bf  = (bf16_t*)alloc((size_t)M_PAD * HID * 2);
    float*  hgat     = (float*)alloc((size_t)M_PAD * HG_LD * 4);
    bf16_t* W1t      = (bf16_t*)alloc((size_t)512 * K1 * 2);
    bf16_t* W2t      = (bf16_t*)alloc((size_t)512 * 512 * 2);
    bf16_t* Bst      = (bf16_t*)alloc((size_t)512 * 1024 * 2);
    bf16_t* Wgt      = (bf16_t*)alloc((size_t)128 * DENSE_F * 2);
    float*  deg      = (float*)alloc((size_t)N_NODES * 4);
    float*  dinv     = (float*)alloc((size_t)N_NODES * 4);
    float*  asrc     = (float*)alloc(32 * 4);
    float*  adst     = (float*)alloc(32 * 4);
    int*    cnt      = (int*)alloc((size_t)N_NODES * 4);
    int*    rowp     = (int*)alloc((size_t)(N_NODES + 1) * 4);
    int*    woff     = (int*)alloc((size_t)N_NODES * 4);
    int*    colx     = (int*)alloc((size_t)N_EDGES * 4);
    float*  wcsr     = (float*)alloc((size_t)N_EDGES * 4);

    const int EB = EB_BLOCKS;

    hipMemsetAsync(deg, 0, (size_t)N_NODES * 4, stream);
    hipMemsetAsync(cnt, 0, (size_t)N_NODES * 4, stream);
    hipMemsetAsync(hgat, 0, (size_t)M_PAD * HG_LD * 4, stream);

    // Fused: build_stats || conv_x || pack_weights
    prologue<<<PRO_BLOCKS, 256, 0, stream>>>(
        dst, ew, deg, cnt, x, x_bf,
        W1, W2, sWl, sWr, g1W, g2W, g1as, g1ad, g2as, g2ad,
        W1t, W2t, Bst, Wgt, asrc, adst);
    // Fused: exclusive scan + node_stats (deg+1, rsqrt)
    scan_rowptr_fast<<<1, 1024, 0, stream>>>(cnt, rowp, woff, deg, dinv);
    scatter_csr<<<EB, 256, 0, stream>>>(src, dst, ew, woff, colx, wcsr);

    const dim3 gB(256);
    const dim3 g512(HID / 128, M_PAD / 128);      // (4, 235)
    const dim3 g128z(1, M_PAD / 128, 2);          // split-K x2 for GAT gemm

    // GCN1 (commuted): aggx = A_gcn * x ; x1 = relu(aggx@W1 + b1) -> dense[:,0:512]
    agg_x<<<N_NODES / 4, 256, 0, stream>>>(x_bf, rowp, colx, wcsr, dinv, deg, aggx_bf);
    gemm_bf16<<<g512, gB, 0, stream>>>(aggx_bf, K1, K1, aggx_bf, K1, W1t, K1,
                                       dense, dense_bf, DENSE_F, K1, b1, 512, 0);

    // Fused x1 gather: g = A_gcn * x1 (GCN2), mean = mean(x1) (SAGE)
    agg_x1<<<N_NODES / 4, 256, 0, stream>>>(dense_bf, rowp, colx, wcsr, dinv, deg, cnt,
                                            g_bf, mean_bf);
    // GCN2 (commuted): x2 = relu(g@W2 + b2) -> dense[:,512:1024]
    gemm_bf16<<<g512, gB, 0, stream>>>(g_bf, HID, HID, g_bf, HID, W2t, HID,
                                       dense + HID, dense_bf + HID, DENSE_F,
                                       HID, b2, 512, 0);
    // SAGE: x3 = relu([mean|x1]@[Wl;Wr] + sb) -> dense[:,1024:1536]
    gemm_bf16<<<g512, gB, 0, stream>>>(mean_bf, HID, HID, dense_bf, DENSE_F,
                                       Bst, 1024, dense + 2 * HID,
                                       dense_bf + 2 * HID, DENSE_F, 1024, sb, 512, 0);

    // GAT: hgat = dense @ Wg (fp32, masked to 32 cols, stride 32), split-K x2
    // with atomicAdd accumulation into zeroed hgat; then aggregate.
    gemm_bf16<<<g128z, gB, 0, stream>>>(dense_bf, DENSE_F, DENSE_F, dense_bf, DENSE_F,
                                        Wgt, DENSE_F, hgat, nullptr, HG_LD,
                                        DENSE_F, nullptr, HG_LD, 1);
    gat_agg<<<N_NODES / 4, 256, 0, stream>>>(hgat, rowp, colx, asrc, adst, g1b, g2b, xout);
}

// Round 2
// 828.291 us; speedup vs baseline: 1.0113x; 1.0113x over previous
//
#include <hip/hip_runtime.h>
#include <hip/hip_bf16.h>
#include <stdint.h>

#define N_NODES 30000
#define M_PAD   30080      // 235 * 128, GEMM M padding
#define N_EDGES 480000
#define F_IN 376
#define K1   384           // F_IN padded to BK multiple
#define HID 512
#define DENSE_F 1536
#define NHEADS 20          // 4 (gat1) + 16 (gat2)
#define HG_LD 32           // hgat leading dim (fp32): 3.85 MB, L2-resident

typedef __bf16 bf16_t;
typedef bf16_t bf16x8 __attribute__((ext_vector_type(8)));
typedef float  f32x4  __attribute__((ext_vector_type(4)));

#define S1 (512 * K1)
#define S2 (512 * 512)
#define S3 (512 * 1024)
#define S4 (128 * DENSE_F)
#define PW_ELEMS (S1 + S2 + S3 + S4 + NHEADS)

#define EB_BLOCKS ((N_EDGES + 255) / 256)
#define CX_BLOCKS ((M_PAD * K1) / 256)           // 45120 exactly
#define PW_BLOCKS ((PW_ELEMS + 255) / 256)
#define PRO_BLOCKS (EB_BLOCKS + CX_BLOCKS + PW_BLOCKS)

// ---------------------------------------------------------------------------
// Fused prologue: three independent stages run concurrently in one launch.
//   [0, EB)           build_stats : deg/cnt atomics over edges
//   [EB, EB+CX)       conv_x      : x fp32 -> x_bf bf16 padded
//   [EB+CX, ...)      pack_weights: all weight transposes/padding
// ---------------------------------------------------------------------------
__global__ __launch_bounds__(256) void prologue(
    const int* __restrict__ dst, const float* __restrict__ ew,
    float* __restrict__ deg, int* __restrict__ cnt,
    const float* __restrict__ x, bf16_t* __restrict__ xb,
    const float* __restrict__ W1, const float* __restrict__ W2,
    const float* __restrict__ Wl, const float* __restrict__ Wr,
    const float* __restrict__ g1W, const float* __restrict__ g2W,
    const float* __restrict__ a1s, const float* __restrict__ a1d,
    const float* __restrict__ a2s, const float* __restrict__ a2d,
    bf16_t* __restrict__ W1t, bf16_t* __restrict__ W2t,
    bf16_t* __restrict__ Bst, bf16_t* __restrict__ Wgt,
    float* __restrict__ asrc, float* __restrict__ adst)
{
    int b = blockIdx.x;
    if (b < EB_BLOCKS) {
        int e = b * 256 + threadIdx.x;
        if (e >= N_EDGES) return;
        int t = dst[e];
        atomicAdd(&deg[t], ew[e]);
        atomicAdd(&cnt[t], 1);
    } else if (b < EB_BLOCKS + CX_BLOCKS) {
        int tid = (b - EB_BLOCKS) * 256 + threadIdx.x;
        int r = tid / K1, c = tid - r * K1;
        float v = (r < N_NODES && c < F_IN) ? x[r * F_IN + c] : 0.f;
        xb[tid] = (bf16_t)v;
    } else {
        int tid = (b - EB_BLOCKS - CX_BLOCKS) * 256 + threadIdx.x;
        if (tid < S1) {
            int n = tid / K1, k = tid - n * K1;
            W1t[tid] = (bf16_t)((k < F_IN) ? W1[k * HID + n] : 0.f);
        } else if (tid < S1 + S2) {
            int t = tid - S1;
            int n = t >> 9, k = t & 511;
            W2t[t] = (bf16_t)W2[k * HID + n];
        } else if (tid < S1 + S2 + S3) {
            int t = tid - S1 - S2;
            int n = t >> 10, k = t & 1023;
            Bst[t] = (bf16_t)((k < HID) ? Wl[k * HID + n] : Wr[(k - HID) * HID + n]);
        } else if (tid < S1 + S2 + S3 + S4) {
            int t = tid - S1 - S2 - S3;
            int n = t / DENSE_F, k = t - n * DENSE_F;
            float v = (n < 4) ? g1W[k * 4 + n] : (n < NHEADS) ? g2W[k * 16 + (n - 4)] : 0.f;
            Wgt[t] = (bf16_t)v;
        } else if (tid < S1 + S2 + S3 + S4 + NHEADS) {
            int hh = tid - S1 - S2 - S3 - S4;
            asrc[hh] = (hh < 4) ? a1s[hh] : a2s[hh - 4];
            adst[hh] = (hh < 4) ? a1d[hh] : a2d[hh - 4];
        }
    }
}

// ---------------------------------------------------------------------------
// Fast exclusive scan of cnt -> rowptr/woff, + node_stats fold (deg+1, rsqrt).
// 1 block, 1024 threads, each thread owns SEG=30 contiguous elements.
// ---------------------------------------------------------------------------
#define SEG 30
__global__ __launch_bounds__(1024) void scan_rowptr_fast(
    const int* __restrict__ cnt, int* __restrict__ rowptr, int* __restrict__ woff,
    float* __restrict__ deg, float* __restrict__ dinv)
{
    int t = threadIdx.x;
    int base = t * SEG;
    int v[SEG];
    int sum = 0;
#pragma unroll
    for (int j = 0; j < SEG; ++j) {
        int i = base + j;
        int c = (i < N_NODES) ? cnt[i] : 0;
        v[j] = c;
        sum += c;
        if (i < N_NODES) {
            float d = deg[i] + 1.0f;   // self-loop weight 1
            deg[i] = d;
            dinv[i] = rsqrtf(d);
        }
    }
    int lane = t & 63;
    int wid = t >> 6;
    int s = sum;
#pragma unroll
    for (int off = 1; off < 64; off <<= 1) {
        int u = __shfl_up(s, off);
        if (lane >= off) s += u;
    }
    __shared__ int wsum[16];
    if (lane == 63) wsum[wid] = s;
    __syncthreads();
    if (t < 16) {
        int ws = wsum[t];
#pragma unroll
        for (int off = 1; off < 16; off <<= 1) {
            int u = __shfl_up(ws, off);
            if (t >= off) ws += u;
        }
        wsum[t] = ws;
    }
    __syncthreads();
    int carry = (wid > 0) ? wsum[wid - 1] : 0;
    int excl = carry + s - sum;   // exclusive prefix for this thread's segment
#pragma unroll
    for (int j = 0; j < SEG; ++j) {
        int i = base + j;
        if (i < N_NODES) { rowptr[i] = excl; woff[i] = excl; }
        excl += v[j];
    }
    if (t == 1023) rowptr[N_NODES] = excl;   // total edge count
}

__global__ __launch_bounds__(256) void scatter_csr(
    const int* __restrict__ src, const int* __restrict__ dst,
    const float* __restrict__ ew, int* __restrict__ woff,
    int* __restrict__ col, float* __restrict__ wcsr)
{
    int e = blockIdx.x * 256 + threadIdx.x;
    if (e >= N_EDGES) return;
    int t = dst[e];
    int p = atomicAdd(&woff[t], 1);
    col[p] = src[e];
    wcsr[p] = ew[e];
}

// ---------------------------------------------------------------------------
// bf16 MFMA GEMM (NT) body with fused epilogue:
//   acc = A * Bt^T  (fp32)
//   if bias: v = relu(acc + bias[col]) else v = acc
//   if C : C [row*ldc+col] = v   (fp32), col < ncols, row < N_NODES
//   if Cb: Cb[row*ldc+col] = v   (bf16)
// 128x128 tile, BK=32, 4 waves, 16x16x32 MFMA, global_load_lds staging.
// A has two k-segments (ksplit) to fuse SAGE's mean@Wl + x1@Wr.
// ---------------------------------------------------------------------------
__device__ __forceinline__ void gemm_body(
    const bf16_t* __restrict__ A1, int lda1, int ksplit,
    const bf16_t* __restrict__ A2, int lda2,
    const bf16_t* __restrict__ Bt, int ldb,
    float* __restrict__ C, bf16_t* __restrict__ Cb, long ldc, int K,
    const float* __restrict__ bias, int ncols,
    int n0, long r0, bf16_t* As, bf16_t* Bs)
{
    const int tid = threadIdx.x;
    const int wid = tid >> 6, lane = tid & 63;
    const int li = lane & 15, kq = lane >> 4;
    const int wm = (wid >> 1) * 64, wn = (wid & 1) * 64;

    f32x4 acc[4][4] = {};

    const int s0 = wid * 64 + lane;
    const int s1 = 256 + s0;
    const int am0 = s0 >> 2, ak0 = (s0 & 3) ^ ((am0 >> 1) & 3);
    const int am1 = s1 >> 2, ak1 = (s1 & 3) ^ ((am1 >> 1) & 3);
    const int swz = (li >> 1) & 3;

    for (int k0 = 0; k0 < K; k0 += 32) {
        const bf16_t* Ab; int lda;
        if (k0 < ksplit) { Ab = A1 + k0;            lda = lda1; }
        else             { Ab = A2 + (k0 - ksplit); lda = lda2; }
        __builtin_amdgcn_global_load_lds(
            (const __attribute__((address_space(1))) void*)(Ab + (r0 + am0) * (long)lda + ak0 * 8),
            (__attribute__((address_space(3))) void*)(As + (wid * 64) * 8), 16, 0, 0);
        __builtin_amdgcn_global_load_lds(
            (const __attribute__((address_space(1))) void*)(Ab + (r0 + am1) * (long)lda + ak1 * 8),
            (__attribute__((address_space(3))) void*)(As + (256 + wid * 64) * 8), 16, 0, 0);
        __builtin_amdgcn_global_load_lds(
            (const __attribute__((address_space(1))) void*)(Bt + (n0 + am0) * (long)ldb + k0 + ak0 * 8),
            (__attribute__((address_space(3))) void*)(Bs + (wid * 64) * 8), 16, 0, 0);
        __builtin_amdgcn_global_load_lds(
            (const __attribute__((address_space(1))) void*)(Bt + (n0 + am1) * (long)ldb + k0 + ak1 * 8),
            (__attribute__((address_space(3))) void*)(Bs + (256 + wid * 64) * 8), 16, 0, 0);
        __syncthreads();

        bf16x8 a[4], b[4];
#pragma unroll
        for (int f = 0; f < 4; ++f) {
            int m = wm + f * 16 + li;
            a[f] = *(const bf16x8*)(As + m * 32 + ((kq ^ swz) * 8));
            int n = wn + f * 16 + li;
            b[f] = *(const bf16x8*)(Bs + n * 32 + ((kq ^ swz) * 8));
        }
#pragma unroll
        for (int fm = 0; fm < 4; ++fm)
#pragma unroll
            for (int fn = 0; fn < 4; ++fn)
                acc[fm][fn] = __builtin_amdgcn_mfma_f32_16x16x32_bf16(
                    a[fm], b[fn], acc[fm][fn], 0, 0, 0);
        __syncthreads();
    }

    // C/D layout: col = lane&15, row = (lane>>4)*4 + reg
#pragma unroll
    for (int fm = 0; fm < 4; ++fm) {
#pragma unroll
        for (int r = 0; r < 4; ++r) {
            long row = r0 + wm + fm * 16 + kq * 4 + r;
            if (row >= N_NODES) continue;
#pragma unroll
            for (int fn = 0; fn < 4; ++fn) {
                int colg = n0 + wn + fn * 16 + li;
                if (colg >= ncols) continue;
                float v = acc[fm][fn][r];
                if (bias) v = fmaxf(v + bias[colg], 0.f);
                if (C)  C[row * ldc + colg]  = v;
                if (Cb) Cb[row * ldc + colg] = (bf16_t)v;
            }
        }
    }
}

__global__ __launch_bounds__(256) void gemm_bf16(
    const bf16_t* __restrict__ A1, int lda1, int ksplit,
    const bf16_t* __restrict__ A2, int lda2,
    const bf16_t* __restrict__ Bt, int ldb,
    float* __restrict__ C, bf16_t* __restrict__ Cb, long ldc, int K,
    const float* __restrict__ bias, int ncols)
{
    __shared__ bf16_t As[128 * 32];
    __shared__ bf16_t Bs[128 * 32];
    gemm_body(A1, lda1, ksplit, A2, lda2, Bt, ldb, C, Cb, ldc, K, bias, ncols,
              blockIdx.x * 128, (long)blockIdx.y * 128, As, Bs);
}

// Two independent GEMMs (GCN2 + SAGE) in one launch: blockIdx.x<4 -> set 0.
__global__ __launch_bounds__(256) void gemm_bf16_dual(
    const bf16_t* __restrict__ A1a, int lda1a, int ksplita,
    const bf16_t* __restrict__ A2a, int lda2a,
    const bf16_t* __restrict__ Bta, int ldba,
    float* __restrict__ Ca, bf16_t* __restrict__ Cba, long ldca, int Ka,
    const float* __restrict__ biasa, int ncolsa,
    const bf16_t* __restrict__ A1b, int lda1b, int ksplitb,
    const bf16_t* __restrict__ A2b, int lda2b,
    const bf16_t* __restrict__ Btb, int ldbb,
    float* __restrict__ Cb2, bf16_t* __restrict__ Cbb, long ldcb, int Kb,
    const float* __restrict__ biasb, int ncolsb)
{
    __shared__ bf16_t As[128 * 32];
    __shared__ bf16_t Bs[128 * 32];
    long r0 = (long)blockIdx.y * 128;
    if (blockIdx.x < 4) {
        gemm_body(A1a, lda1a, ksplita, A2a, lda2a, Bta, ldba, Ca, Cba, ldca, Ka,
                  biasa, ncolsa, blockIdx.x * 128, r0, As, Bs);
    } else {
        gemm_body(A1b, lda1b, ksplitb, A2b, lda2b, Btb, ldbb, Cb2, Cbb, ldcb, Kb,
                  biasb, ncolsb, (blockIdx.x - 4) * 128, r0, As, Bs);
    }
}

// ---------------------------------------------------------------------------
// GCN aggregation over raw x_bf (384 cols): aggx[i] = x[i]/deg + sum norm*x[s]
// 4 nodes per 256-thread block (one wave each); 4-edge unroll for MLP.
// ---------------------------------------------------------------------------
__global__ __launch_bounds__(256) void agg_x(
    const bf16_t* __restrict__ xb, const int* __restrict__ rowptr,
    const int* __restrict__ col, const float* __restrict__ wcsr,
    const float* __restrict__ dinv, const float* __restrict__ deg,
    bf16_t* __restrict__ aggx)
{
    int i = blockIdx.x * 4 + (threadIdx.x >> 6);
    int lane = threadIdx.x & 63;
    int c = lane * 8;
    bool act = (c < K1);
    float di = dinv[i];
    float selfw = 1.0f / deg[i];
    float acc0[8] = {}, acc1[8] = {};
    if (act) {
        bf16x8 sv = *(const bf16x8*)(xb + (long)i * K1 + c);
#pragma unroll
        for (int j = 0; j < 8; ++j) acc0[j] = selfw * (float)sv[j];
    }
    int e = rowptr[i], e1 = rowptr[i + 1];
    for (; e + 3 < e1; e += 4) {
        int sA = col[e], sB = col[e + 1], sC = col[e + 2], sD = col[e + 3];
        float wA = dinv[sA] * wcsr[e]     * di;
        float wB = dinv[sB] * wcsr[e + 1] * di;
        float wC = dinv[sC] * wcsr[e + 2] * di;
        float wD = dinv[sD] * wcsr[e + 3] * di;
        if (act) {
            bf16x8 vA = *(const bf16x8*)(xb + (long)sA * K1 + c);
            bf16x8 vB = *(const bf16x8*)(xb + (long)sB * K1 + c);
            bf16x8 vC = *(const bf16x8*)(xb + (long)sC * K1 + c);
            bf16x8 vD = *(const bf16x8*)(xb + (long)sD * K1 + c);
#pragma unroll
            for (int j = 0; j < 8; ++j) {
                acc0[j] = fmaf(wA, (float)vA[j], acc0[j]);
                acc1[j] = fmaf(wB, (float)vB[j], acc1[j]);
                acc0[j] = fmaf(wC, (float)vC[j], acc0[j]);
                acc1[j] = fmaf(wD, (float)vD[j], acc1[j]);
            }
        }
    }
    for (; e < e1; ++e) {
        int sA = col[e];
        float wA = dinv[sA] * wcsr[e] * di;
        if (act) {
            bf16x8 vA = *(const bf16x8*)(xb + (long)sA * K1 + c);
#pragma unroll
            for (int j = 0; j < 8; ++j) acc0[j] = fmaf(wA, (float)vA[j], acc0[j]);
        }
    }
    if (act) {
        bf16x8 ob;
#pragma unroll
        for (int j = 0; j < 8; ++j) ob[j] = (bf16_t)(acc0[j] + acc1[j]);
        *reinterpret_cast<bf16x8*>(aggx + (long)i * K1 + c) = ob;
    }
}

// ---------------------------------------------------------------------------
// Fused x1 aggregation: ONE gather of x1 rows serves GCN2 (norm-weighted sum
// + self) AND SAGE (plain mean). 4 nodes/block, 4-edge unroll.
// ---------------------------------------------------------------------------
__global__ __launch_bounds__(256) void agg_x1(
    const bf16_t* __restrict__ x1b /* dense_bf, cols [0,512) */,
    const int* __restrict__ rowptr, const int* __restrict__ col,
    const float* __restrict__ wcsr, const float* __restrict__ dinv,
    const float* __restrict__ deg, const int* __restrict__ cnt,
    bf16_t* __restrict__ gbf, bf16_t* __restrict__ meanb)
{
    int i = blockIdx.x * 4 + (threadIdx.x >> 6);
    int lane = threadIdx.x & 63;
    int c = lane * 8;
    float di = dinv[i];
    float selfw = 1.0f / deg[i];
    bf16x8 sv = *(const bf16x8*)(x1b + (long)i * DENSE_F + c);
    float g0[8], g1[8], m0[8], m1[8];
#pragma unroll
    for (int j = 0; j < 8; ++j) {
        g0[j] = selfw * (float)sv[j];
        g1[j] = 0.f; m0[j] = 0.f; m1[j] = 0.f;
    }
    int e = rowptr[i], e1 = rowptr[i + 1];
    for (; e + 3 < e1; e += 4) {
        int sA = col[e], sB = col[e + 1], sC = col[e + 2], sD = col[e + 3];
        float wA = dinv[sA] * wcsr[e]     * di;
        float wB = dinv[sB] * wcsr[e + 1] * di;
        float wC = dinv[sC] * wcsr[e + 2] * di;
        float wD = dinv[sD] * wcsr[e + 3] * di;
        bf16x8 vA = *(const bf16x8*)(x1b + (long)sA * DENSE_F + c);
        bf16x8 vB = *(const bf16x8*)(x1b + (long)sB * DENSE_F + c);
        bf16x8 vC = *(const bf16x8*)(x1b + (long)sC * DENSE_F + c);
        bf16x8 vD = *(const bf16x8*)(x1b + (long)sD * DENSE_F + c);
#pragma unroll
        for (int j = 0; j < 8; ++j) {
            float fA = (float)vA[j], fB = (float)vB[j];
            float fC = (float)vC[j], fD = (float)vD[j];
            g0[j] = fmaf(wA, fA, g0[j]);
            g1[j] = fmaf(wB, fB, g1[j]);
            g0[j] = fmaf(wC, fC, g0[j]);
            g1[j] = fmaf(wD, fD, g1[j]);
            m0[j] += fA + fC;
            m1[j] += fB + fD;
        }
    }
    for (; e < e1; ++e) {
        int sA = col[e];
        float wA = dinv[sA] * wcsr[e] * di;
        bf16x8 vA = *(const bf16x8*)(x1b + (long)sA * DENSE_F + c);
#pragma unroll
        for (int j = 0; j < 8; ++j) {
            float fA = (float)vA[j];
            g0[j] = fmaf(wA, fA, g0[j]);
            m0[j] += fA;
        }
    }
    float inv = 1.0f / fmaxf((float)cnt[i], 1.0f);
    bf16x8 og, om;
#pragma unroll
    for (int j = 0; j < 8; ++j) {
        og[j] = (bf16_t)(g0[j] + g1[j]);
        om[j] = (bf16_t)((m0[j] + m1[j]) * inv);
    }
    *reinterpret_cast<bf16x8*>(gbf   + (long)i * HID + c) = og;
    *reinterpret_cast<bf16x8*>(meanb + (long)i * HID + c) = om;
}

// per-dst GAT attention over CSR (+self loop), softmax shift-free,
// hgat stride HG_LD=32 (3.85 MB, L2-resident), 4-edge unroll.
// 4 nodes per 256-thread block (one wave each).
__global__ __launch_bounds__(256) void gat_agg(
    const float* __restrict__ hgat, const int* __restrict__ rowptr,
    const int* __restrict__ col, const float* __restrict__ asrc,
    const float* __restrict__ adst, const float* __restrict__ b1p,
    const float* __restrict__ b2p, float* __restrict__ xout)
{
    int i = blockIdx.x * 4 + (threadIdx.x >> 6);
    int lane = threadIdx.x & 63;
    int h = (lane < NHEADS) ? lane : 0;
    float hg_i = hgat[(long)i * HG_LD + h];
    float as = asrc[h], ad = adst[h];
    float adhg = ad * hg_i;
    float ev = hg_i * as + adhg;
    ev = ev > 0.f ? ev : 0.2f * ev;
    float ex = __expf(ev);
    float den0 = ex, og0 = ex * hg_i, den1 = 0.f, og1 = 0.f;
    int e = rowptr[i], e1 = rowptr[i + 1];
    for (; e + 3 < e1; e += 4) {
        int sA = col[e], sB = col[e + 1], sC = col[e + 2], sD = col[e + 3];
        float hA = hgat[(long)sA * HG_LD + h];
        float hB = hgat[(long)sB * HG_LD + h];
        float hC = hgat[(long)sC * HG_LD + h];
        float hD = hgat[(long)sD * HG_LD + h];
        float tA = fmaf(hA, as, adhg); tA = tA > 0.f ? tA : 0.2f * tA;
        float tB = fmaf(hB, as, adhg); tB = tB > 0.f ? tB : 0.2f * tB;
        float tC = fmaf(hC, as, adhg); tC = tC > 0.f ? tC : 0.2f * tC;
        float tD = fmaf(hD, as, adhg); tD = tD > 0.f ? tD : 0.2f * tD;
        float xA = __expf(tA), xB = __expf(tB);
        float xC = __expf(tC), xD = __expf(tD);
        den0 += xA; og0 = fmaf(xA, hA, og0);
        den1 += xB; og1 = fmaf(xB, hB, og1);
        den0 += xC; og0 = fmaf(xC, hC, og0);
        den1 += xD; og1 = fmaf(xD, hD, og1);
    }
    for (; e < e1; ++e) {
        int sA = col[e];
        float hA = hgat[(long)sA * HG_LD + h];
        float tA = fmaf(hA, as, adhg); tA = tA > 0.f ? tA : 0.2f * tA;
        float xA = __expf(tA);
        den0 += xA; og0 = fmaf(xA, hA, og0);
    }
    float out = (lane < NHEADS) ? (og0 + og1) / (den0 + den1) : 0.f;
    float s4 = out + __shfl_xor(out, 1);
    s4 += __shfl_xor(s4, 2);
    float g0 = __shfl(s4, 0);
    float g1 = __shfl(s4, 4);
    float g2 = __shfl(s4, 8);
    float g3 = __shfl(s4, 12);
    float g4 = __shfl(s4, 16);
    if (lane == 0) {
        float a1 = g0 * 0.25f + b1p[0];
        float a2 = (g1 + g2 + g3 + g4) * 0.0625f + b2p[0];
        xout[i] = 0.5f * (a1 + a2);
    }
}

// ---------------------------------------------------------------------------
extern "C" void kernel_launch(void* const* d_in, const int* in_sizes, int n_in,
                              void* d_out, int out_size, void* d_ws, size_t ws_size,
                              hipStream_t stream) {
    (void)in_sizes; (void)n_in; (void)out_size; (void)ws_size;
    const float* x    = (const float*)d_in[0];
    const int*   ei   = (const int*)d_in[1];
    const float* ew   = (const float*)d_in[2];
    const float* W1   = (const float*)d_in[3];
    const float* b1   = (const float*)d_in[4];
    const float* W2   = (const float*)d_in[5];
    const float* b2   = (const float*)d_in[6];
    const float* sWl  = (const float*)d_in[7];
    const float* sWr  = (const float*)d_in[8];
    const float* sb   = (const float*)d_in[9];
    const float* g1W  = (const float*)d_in[10];
    const float* g1as = (const float*)d_in[11];
    const float* g1ad = (const float*)d_in[12];
    const float* g1b  = (const float*)d_in[13];
    const float* g2W  = (const float*)d_in[14];
    const float* g2as = (const float*)d_in[15];
    const float* g2ad = (const float*)d_in[16];
    const float* g2b  = (const float*)d_in[17];

    const int* src = ei;
    const int* dst = ei + N_EDGES;

    float* xout  = (float*)d_out;          // [N]
    float* dense = xout + N_NODES;         // [N,1536] fp32 (output 2)

    size_t off = 0;
    auto alloc = [&](size_t nbytes) -> void* {
        void* p = (char*)d_ws + off;
        off += (nbytes + 255) & ~(size_t)255;
        return p;
    };
    bf16_t* dense_bf = (bf16_t*)alloc((size_t)M_PAD * DENSE_F * 2);
    bf16_t* x_bf     = (bf16_t*)alloc((size_t)M_PAD * K1 * 2);
    bf16_t* aggx_bf  = (bf16_t*)alloc((size_t)M_PAD * K1 * 2);
    bf16_t* g_bf     = (bf16_t*)alloc((size_t)M_PAD * HID * 2);
    bf16_t* mean_bf  = (bf16_t*)alloc((size_t)M_PAD * HID * 2);
    float*  hgat     = (float*)alloc((size_t)M_PAD * HG_LD * 4);
    bf16_t* W1t      = (bf16_t*)alloc((size_t)512 * K1 * 2);
    bf16_t* W2t      = (bf16_t*)alloc((size_t)512 * 512 * 2);
    bf16_t* Bst      = (bf16_t*)alloc((size_t)512 * 1024 * 2);
    bf16_t* Wgt      = (bf16_t*)alloc((size_t)128 * DENSE_F * 2);
    float*  deg      = (float*)alloc((size_t)N_NODES * 4);
    float*  dinv     = (float*)alloc((size_t)N_NODES * 4);
    float*  asrc     = (float*)alloc(32 * 4);
    float*  adst     = (float*)alloc(32 * 4);
    int*    cnt      = (int*)alloc((size_t)N_NODES * 4);
    int*    rowp     = (int*)alloc((size_t)(N_NODES + 1) * 4);
    int*    woff     = (int*)alloc((size_t)N_NODES * 4);
    int*    colx     = (int*)alloc((size_t)N_EDGES * 4);
    float*  wcsr     = (float*)alloc((size_t)N_EDGES * 4);

    const int EB = EB_BLOCKS;

    hipMemsetAsync(deg, 0, (size_t)N_NODES * 4, stream);
    hipMemsetAsync(cnt, 0, (size_t)N_NODES * 4, stream);

    // Fused: build_stats || conv_x || pack_weights
    prologue<<<PRO_BLOCKS, 256, 0, stream>>>(
        dst, ew, deg, cnt, x, x_bf,
        W1, W2, sWl, sWr, g1W, g2W, g1as, g1ad, g2as, g2ad,
        W1t, W2t, Bst, Wgt, asrc, adst);
    // Fused: exclusive scan + node_stats (deg+1, rsqrt)
    scan_rowptr_fast<<<1, 1024, 0, stream>>>(cnt, rowp, woff, deg, dinv);
    scatter_csr<<<EB, 256, 0, stream>>>(src, dst, ew, woff, colx, wcsr);

    const dim3 gB(256);
    const dim3 g512(HID / 128, M_PAD / 128);      // (4, 235)
    const dim3 gdual(8, M_PAD / 128);             // (8, 235): GCN2 + SAGE
    const dim3 g128(1, M_PAD / 128);              // (1, 235): GAT

    // GCN1 (commuted): aggx = A_gcn * x ; x1 = relu(aggx@W1 + b1) -> dense[:,0:512]
    agg_x<<<N_NODES / 4, 256, 0, stream>>>(x_bf, rowp, colx, wcsr, dinv, deg, aggx_bf);
    gemm_bf16<<<g512, gB, 0, stream>>>(aggx_bf, K1, K1, aggx_bf, K1, W1t, K1,
                                       dense, dense_bf, DENSE_F, K1, b1, 512);

    // Fused x1 gather: g = A_gcn * x1 (GCN2), mean = mean(x1) (SAGE)
    agg_x1<<<N_NODES / 4, 256, 0, stream>>>(dense_bf, rowp, colx, wcsr, dinv, deg, cnt,
                                            g_bf, mean_bf);
    // GCN2 + SAGE fused into one launch (independent GEMMs):
    //   x2 = relu(g@W2 + b2)                 -> dense[:,512:1024]
    //   x3 = relu([mean|x1]@[Wl;Wr] + sb)    -> dense[:,1024:1536]
    gemm_bf16_dual<<<gdual, gB, 0, stream>>>(
        g_bf, HID, HID, g_bf, HID, W2t, HID,
        dense + HID, dense_bf + HID, DENSE_F, HID, b2, 512,
        mean_bf, HID, HID, dense_bf, DENSE_F, Bst, 1024,
        dense + 2 * HID, dense_bf + 2 * HID, DENSE_F, 1024, sb, 512);

    // GAT: hgat = dense @ Wg (fp32, masked to 32 cols, stride 32), then aggregate
    gemm_bf16<<<g128, gB, 0, stream>>>(dense_bf, DENSE_F, DENSE_F, dense_bf, DENSE_F,
                                       Wgt, DENSE_F, hgat, nullptr, HG_LD,
                                       DENSE_F, nullptr, HG_LD);
    gat_agg<<<N_NODES / 4, 256, 0, stream>>>(hgat, rowp, colx, asrc, adst, g1b, g2b, xout);
}

// Round 4
// 818.834 us; speedup vs baseline: 1.0230x; 1.0115x over previous
//
#include <hip/hip_runtime.h>
#include <hip/hip_bf16.h>
#include <stdint.h>

#define N_NODES 30000
#define M_PAD   30080      // 235 * 128, GEMM M padding
#define N_EDGES 480000
#define F_IN 376
#define K1   384           // F_IN padded to BK multiple
#define HID 512
#define DENSE_F 1536
#define NHEADS 20          // 4 (gat1) + 16 (gat2)
#define HG_LD 32           // hgat leading dim (fp32): 3.85 MB, L2-resident

typedef __bf16 bf16_t;
typedef bf16_t bf16x8 __attribute__((ext_vector_type(8)));
typedef float  f32x4  __attribute__((ext_vector_type(4)));

#define S1 (512 * K1)
#define S2 (512 * 512)
#define S3 (512 * 1024)
#define S4 (128 * DENSE_F)
#define PW_ELEMS (S1 + S2 + S3 + S4 + NHEADS)

#define EB_BLOCKS ((N_EDGES + 255) / 256)
#define CX_BLOCKS ((M_PAD * K1) / 256)           // 45120 exactly
#define PW_BLOCKS ((PW_ELEMS + 255) / 256)
#define PRO_BLOCKS (EB_BLOCKS + CX_BLOCKS + PW_BLOCKS)

// ---------------------------------------------------------------------------
// Fused prologue: three independent stages run concurrently in one launch.
// ---------------------------------------------------------------------------
__global__ __launch_bounds__(256) void prologue(
    const int* __restrict__ dst, const float* __restrict__ ew,
    float* __restrict__ deg, int* __restrict__ cnt,
    const float* __restrict__ x, bf16_t* __restrict__ xb,
    const float* __restrict__ W1, const float* __restrict__ W2,
    const float* __restrict__ Wl, const float* __restrict__ Wr,
    const float* __restrict__ g1W, const float* __restrict__ g2W,
    const float* __restrict__ a1s, const float* __restrict__ a1d,
    const float* __restrict__ a2s, const float* __restrict__ a2d,
    bf16_t* __restrict__ W1t, bf16_t* __restrict__ W2t,
    bf16_t* __restrict__ Bst, bf16_t* __restrict__ Wgt,
    float* __restrict__ asrc, float* __restrict__ adst)
{
    int b = blockIdx.x;
    if (b < EB_BLOCKS) {
        int e = b * 256 + threadIdx.x;
        if (e >= N_EDGES) return;
        int t = dst[e];
        atomicAdd(&deg[t], ew[e]);
        atomicAdd(&cnt[t], 1);
    } else if (b < EB_BLOCKS + CX_BLOCKS) {
        int tid = (b - EB_BLOCKS) * 256 + threadIdx.x;
        int r = tid / K1, c = tid - r * K1;
        float v = (r < N_NODES && c < F_IN) ? x[r * F_IN + c] : 0.f;
        xb[tid] = (bf16_t)v;
    } else {
        int tid = (b - EB_BLOCKS - CX_BLOCKS) * 256 + threadIdx.x;
        if (tid < S1) {
            int n = tid / K1, k = tid - n * K1;
            W1t[tid] = (bf16_t)((k < F_IN) ? W1[k * HID + n] : 0.f);
        } else if (tid < S1 + S2) {
            int t = tid - S1;
            int n = t >> 9, k = t & 511;
            W2t[t] = (bf16_t)W2[k * HID + n];
        } else if (tid < S1 + S2 + S3) {
            int t = tid - S1 - S2;
            int n = t >> 10, k = t & 1023;
            Bst[t] = (bf16_t)((k < HID) ? Wl[k * HID + n] : Wr[(k - HID) * HID + n]);
        } else if (tid < S1 + S2 + S3 + S4) {
            int t = tid - S1 - S2 - S3;
            int n = t / DENSE_F, k = t - n * DENSE_F;
            float v = (n < 4) ? g1W[k * 4 + n] : (n < NHEADS) ? g2W[k * 16 + (n - 4)] : 0.f;
            Wgt[t] = (bf16_t)v;
        } else if (tid < S1 + S2 + S3 + S4 + NHEADS) {
            int hh = tid - S1 - S2 - S3 - S4;
            asrc[hh] = (hh < 4) ? a1s[hh] : a2s[hh - 4];
            adst[hh] = (hh < 4) ? a1d[hh] : a2d[hh - 4];
        }
    }
}

// ---------------------------------------------------------------------------
// Fast exclusive scan of cnt -> rowptr/woff, + node_stats fold (deg+1, rsqrt).
// ---------------------------------------------------------------------------
#define SEG 30
__global__ __launch_bounds__(1024) void scan_rowptr_fast(
    const int* __restrict__ cnt, int* __restrict__ rowptr, int* __restrict__ woff,
    float* __restrict__ deg, float* __restrict__ dinv)
{
    int t = threadIdx.x;
    int base = t * SEG;
    int v[SEG];
    int sum = 0;
#pragma unroll
    for (int j = 0; j < SEG; ++j) {
        int i = base + j;
        int c = (i < N_NODES) ? cnt[i] : 0;
        v[j] = c;
        sum += c;
        if (i < N_NODES) {
            float d = deg[i] + 1.0f;   // self-loop weight 1
            deg[i] = d;
            dinv[i] = rsqrtf(d);
        }
    }
    int lane = t & 63;
    int wid = t >> 6;
    int s = sum;
#pragma unroll
    for (int off = 1; off < 64; off <<= 1) {
        int u = __shfl_up(s, off);
        if (lane >= off) s += u;
    }
    __shared__ int wsum[16];
    if (lane == 63) wsum[wid] = s;
    __syncthreads();
    if (t < 16) {
        int ws = wsum[t];
#pragma unroll
        for (int off = 1; off < 16; off <<= 1) {
            int u = __shfl_up(ws, off);
            if (t >= off) ws += u;
        }
        wsum[t] = ws;
    }
    __syncthreads();
    int carry = (wid > 0) ? wsum[wid - 1] : 0;
    int excl = carry + s - sum;   // exclusive prefix for this thread's segment
#pragma unroll
    for (int j = 0; j < SEG; ++j) {
        int i = base + j;
        if (i < N_NODES) { rowptr[i] = excl; woff[i] = excl; }
        excl += v[j];
    }
    if (t == 1023) rowptr[N_NODES] = excl;   // total edge count
}

__global__ __launch_bounds__(256) void scatter_csr(
    const int* __restrict__ src, const int* __restrict__ dst,
    const float* __restrict__ ew, int* __restrict__ woff,
    int* __restrict__ col, float* __restrict__ wcsr)
{
    int e = blockIdx.x * 256 + threadIdx.x;
    if (e >= N_EDGES) return;
    int t = dst[e];
    int p = atomicAdd(&woff[t], 1);
    col[p] = src[e];
    wcsr[p] = ew[e];
}

// ---------------------------------------------------------------------------
// bf16 MFMA GEMM (NT) body, DOUBLE-BUFFERED (T3 minimum 2-phase):
//   prologue: stage(buf0, k=0); sync
//   step s  : stage(buf^1, k+1)  ||  ds_read+MFMA from buf[cur]; sync
// One barrier per K-step; global->LDS latency hides under MFMA.
// Race audit: write buf^1@s after barrier s-1 (lgkm drained -> reads done);
// read buf[cur]@s after barrier s-1 (each wave's own vmcnt drained its stage).
// ---------------------------------------------------------------------------
#define TILE_E (128 * 32)
__device__ __forceinline__ void gemm_body(
    const bf16_t* __restrict__ A1, int lda1, int ksplit,
    const bf16_t* __restrict__ A2, int lda2,
    const bf16_t* __restrict__ Bt, int ldb,
    float* __restrict__ C, bf16_t* __restrict__ Cb, long ldc, int K,
    const float* __restrict__ bias, int ncols,
    int n0, long r0, bf16_t* As, bf16_t* Bs)
{
    const int tid = threadIdx.x;
    const int wid = tid >> 6, lane = tid & 63;
    const int li = lane & 15, kq = lane >> 4;
    const int wm = (wid >> 1) * 64, wn = (wid & 1) * 64;

    f32x4 acc[4][4] = {};

    const int s0 = wid * 64 + lane;
    const int s1 = 256 + s0;
    const int am0 = s0 >> 2, ak0 = (s0 & 3) ^ ((am0 >> 1) & 3);
    const int am1 = s1 >> 2, ak1 = (s1 & 3) ^ ((am1 >> 1) & 3);
    const int swz = (li >> 1) & 3;

    auto stage = [&](int buf, int k0) {
        const bf16_t* Ab; int lda;
        if (k0 < ksplit) { Ab = A1 + k0;            lda = lda1; }
        else             { Ab = A2 + (k0 - ksplit); lda = lda2; }
        bf16_t* Asb = As + buf * TILE_E;
        bf16_t* Bsb = Bs + buf * TILE_E;
        __builtin_amdgcn_global_load_lds(
            (const __attribute__((address_space(1))) void*)(Ab + (r0 + am0) * (long)lda + ak0 * 8),
            (__attribute__((address_space(3))) void*)(Asb + (wid * 64) * 8), 16, 0, 0);
        __builtin_amdgcn_global_load_lds(
            (const __attribute__((address_space(1))) void*)(Ab + (r0 + am1) * (long)lda + ak1 * 8),
            (__attribute__((address_space(3))) void*)(Asb + (256 + wid * 64) * 8), 16, 0, 0);
        __builtin_amdgcn_global_load_lds(
            (const __attribute__((address_space(1))) void*)(Bt + (n0 + am0) * (long)ldb + k0 + ak0 * 8),
            (__attribute__((address_space(3))) void*)(Bsb + (wid * 64) * 8), 16, 0, 0);
        __builtin_amdgcn_global_load_lds(
            (const __attribute__((address_space(1))) void*)(Bt + (n0 + am1) * (long)ldb + k0 + ak1 * 8),
            (__attribute__((address_space(3))) void*)(Bsb + (256 + wid * 64) * 8), 16, 0, 0);
    };

    const int nsteps = K >> 5;
    stage(0, 0);
    __syncthreads();           // vmcnt(0) drain: buf0 ready

    int cur = 0;
    for (int s = 0; s < nsteps; ++s) {
        if (s + 1 < nsteps) stage(cur ^ 1, (s + 1) << 5);   // prefetch next

        const bf16_t* Asb = As + cur * TILE_E;
        const bf16_t* Bsb = Bs + cur * TILE_E;
        bf16x8 a[4], b[4];
#pragma unroll
        for (int f = 0; f < 4; ++f) {
            int m = wm + f * 16 + li;
            a[f] = *(const bf16x8*)(Asb + m * 32 + ((kq ^ swz) * 8));
            int n = wn + f * 16 + li;
            b[f] = *(const bf16x8*)(Bsb + n * 32 + ((kq ^ swz) * 8));
        }
#pragma unroll
        for (int fm = 0; fm < 4; ++fm)
#pragma unroll
            for (int fn = 0; fn < 4; ++fn)
                acc[fm][fn] = __builtin_amdgcn_mfma_f32_16x16x32_bf16(
                    a[fm], b[fn], acc[fm][fn], 0, 0, 0);
        __syncthreads();       // drains this wave's vmcnt -> buf^1 ready next step
        cur ^= 1;
    }

    // C/D layout: col = lane&15, row = (lane>>4)*4 + reg
#pragma unroll
    for (int fm = 0; fm < 4; ++fm) {
#pragma unroll
        for (int r = 0; r < 4; ++r) {
            long row = r0 + wm + fm * 16 + kq * 4 + r;
            if (row >= N_NODES) continue;
#pragma unroll
            for (int fn = 0; fn < 4; ++fn) {
                int colg = n0 + wn + fn * 16 + li;
                if (colg >= ncols) continue;
                float v = acc[fm][fn][r];
                if (bias) v = fmaxf(v + bias[colg], 0.f);
                if (C)  C[row * ldc + colg]  = v;
                if (Cb) Cb[row * ldc + colg] = (bf16_t)v;
            }
        }
    }
}

__global__ __launch_bounds__(256) void gemm_bf16(
    const bf16_t* __restrict__ A1, int lda1, int ksplit,
    const bf16_t* __restrict__ A2, int lda2,
    const bf16_t* __restrict__ Bt, int ldb,
    float* __restrict__ C, bf16_t* __restrict__ Cb, long ldc, int K,
    const float* __restrict__ bias, int ncols)
{
    __shared__ bf16_t As[2 * TILE_E];
    __shared__ bf16_t Bs[2 * TILE_E];
    gemm_body(A1, lda1, ksplit, A2, lda2, Bt, ldb, C, Cb, ldc, K, bias, ncols,
              blockIdx.x * 128, (long)blockIdx.y * 128, As, Bs);
}

// Two independent GEMMs (GCN2 + SAGE) in one launch: blockIdx.x<4 -> set 0.
__global__ __launch_bounds__(256) void gemm_bf16_dual(
    const bf16_t* __restrict__ A1a, int lda1a, int ksplita,
    const bf16_t* __restrict__ A2a, int lda2a,
    const bf16_t* __restrict__ Bta, int ldba,
    float* __restrict__ Ca, bf16_t* __restrict__ Cba, long ldca, int Ka,
    const float* __restrict__ biasa, int ncolsa,
    const bf16_t* __restrict__ A1b, int lda1b, int ksplitb,
    const bf16_t* __restrict__ A2b, int lda2b,
    const bf16_t* __restrict__ Btb, int ldbb,
    float* __restrict__ Cb2, bf16_t* __restrict__ Cbb, long ldcb, int Kb,
    const float* __restrict__ biasb, int ncolsb)
{
    __shared__ bf16_t As[2 * TILE_E];
    __shared__ bf16_t Bs[2 * TILE_E];
    long r0 = (long)blockIdx.y * 128;
    if (blockIdx.x < 4) {
        gemm_body(A1a, lda1a, ksplita, A2a, lda2a, Bta, ldba, Ca, Cba, ldca, Ka,
                  biasa, ncolsa, blockIdx.x * 128, r0, As, Bs);
    } else {
        gemm_body(A1b, lda1b, ksplitb, A2b, lda2b, Btb, ldbb, Cb2, Cbb, ldcb, Kb,
                  biasb, ncolsb, (blockIdx.x - 4) * 128, r0, As, Bs);
    }
}

// ---------------------------------------------------------------------------
// GCN aggregation over raw x_bf (384 cols): aggx[i] = x[i]/deg + sum norm*x[s]
// 4 nodes per 256-thread block (one wave each); 4-edge unroll for MLP.
// ---------------------------------------------------------------------------
__global__ __launch_bounds__(256) void agg_x(
    const bf16_t* __restrict__ xb, const int* __restrict__ rowptr,
    const int* __restrict__ col, const float* __restrict__ wcsr,
    const float* __restrict__ dinv, const float* __restrict__ deg,
    bf16_t* __restrict__ aggx)
{
    int i = blockIdx.x * 4 + (threadIdx.x >> 6);
    int lane = threadIdx.x & 63;
    int c = lane * 8;
    bool act = (c < K1);
    float di = dinv[i];
    float selfw = 1.0f / deg[i];
    float acc0[8] = {}, acc1[8] = {};
    if (act) {
        bf16x8 sv = *(const bf16x8*)(xb + (long)i * K1 + c);
#pragma unroll
        for (int j = 0; j < 8; ++j) acc0[j] = selfw * (float)sv[j];
    }
    int e = rowptr[i], e1 = rowptr[i + 1];
    for (; e + 3 < e1; e += 4) {
        int sA = col[e], sB = col[e + 1], sC = col[e + 2], sD = col[e + 3];
        float wA = dinv[sA] * wcsr[e]     * di;
        float wB = dinv[sB] * wcsr[e + 1] * di;
        float wC = dinv[sC] * wcsr[e + 2] * di;
        float wD = dinv[sD] * wcsr[e + 3] * di;
        if (act) {
            bf16x8 vA = *(const bf16x8*)(xb + (long)sA * K1 + c);
            bf16x8 vB = *(const bf16x8*)(xb + (long)sB * K1 + c);
            bf16x8 vC = *(const bf16x8*)(xb + (long)sC * K1 + c);
            bf16x8 vD = *(const bf16x8*)(xb + (long)sD * K1 + c);
#pragma unroll
            for (int j = 0; j < 8; ++j) {
                acc0[j] = fmaf(wA, (float)vA[j], acc0[j]);
                acc1[j] = fmaf(wB, (float)vB[j], acc1[j]);
                acc0[j] = fmaf(wC, (float)vC[j], acc0[j]);
                acc1[j] = fmaf(wD, (float)vD[j], acc1[j]);
            }
        }
    }
    for (; e < e1; ++e) {
        int sA = col[e];
        float wA = dinv[sA] * wcsr[e] * di;
        if (act) {
            bf16x8 vA = *(const bf16x8*)(xb + (long)sA * K1 + c);
#pragma unroll
            for (int j = 0; j < 8; ++j) acc0[j] = fmaf(wA, (float)vA[j], acc0[j]);
        }
    }
    if (act) {
        bf16x8 ob;
#pragma unroll
        for (int j = 0; j < 8; ++j) ob[j] = (bf16_t)(acc0[j] + acc1[j]);
        *reinterpret_cast<bf16x8*>(aggx + (long)i * K1 + c) = ob;
    }
}

// ---------------------------------------------------------------------------
// Fused x1 aggregation: ONE gather of x1 rows serves GCN2 (norm-weighted sum
// + self) AND SAGE (plain mean). 4 nodes/block, 4-edge unroll.
// ---------------------------------------------------------------------------
__global__ __launch_bounds__(256) void agg_x1(
    const bf16_t* __restrict__ x1b /* dense_bf, cols [0,512) */,
    const int* __restrict__ rowptr, const int* __restrict__ col,
    const float* __restrict__ wcsr, const float* __restrict__ dinv,
    const float* __restrict__ deg, const int* __restrict__ cnt,
    bf16_t* __restrict__ gbf, bf16_t* __restrict__ meanb)
{
    int i = blockIdx.x * 4 + (threadIdx.x >> 6);
    int lane = threadIdx.x & 63;
    int c = lane * 8;
    float di = dinv[i];
    float selfw = 1.0f / deg[i];
    bf16x8 sv = *(const bf16x8*)(x1b + (long)i * DENSE_F + c);
    float g0[8], g1[8], m0[8], m1[8];
#pragma unroll
    for (int j = 0; j < 8; ++j) {
        g0[j] = selfw * (float)sv[j];
        g1[j] = 0.f; m0[j] = 0.f; m1[j] = 0.f;
    }
    int e = rowptr[i], e1 = rowptr[i + 1];
    for (; e + 3 < e1; e += 4) {
        int sA = col[e], sB = col[e + 1], sC = col[e + 2], sD = col[e + 3];
        float wA = dinv[sA] * wcsr[e]     * di;
        float wB = dinv[sB] * wcsr[e + 1] * di;
        float wC = dinv[sC] * wcsr[e + 2] * di;
        float wD = dinv[sD] * wcsr[e + 3] * di;
        bf16x8 vA = *(const bf16x8*)(x1b + (long)sA * DENSE_F + c);
        bf16x8 vB = *(const bf16x8*)(x1b + (long)sB * DENSE_F + c);
        bf16x8 vC = *(const bf16x8*)(x1b + (long)sC * DENSE_F + c);
        bf16x8 vD = *(const bf16x8*)(x1b + (long)sD * DENSE_F + c);
#pragma unroll
        for (int j = 0; j < 8; ++j) {
            float fA = (float)vA[j], fB = (float)vB[j];
            float fC = (float)vC[j], fD = (float)vD[j];
            g0[j] = fmaf(wA, fA, g0[j]);
            g1[j] = fmaf(wB, fB, g1[j]);
            g0[j] = fmaf(wC, fC, g0[j]);
            g1[j] = fmaf(wD, fD, g1[j]);
            m0[j] += fA + fC;
            m1[j] += fB + fD;
        }
    }
    for (; e < e1; ++e) {
        int sA = col[e];
        float wA = dinv[sA] * wcsr[e] * di;
        bf16x8 vA = *(const bf16x8*)(x1b + (long)sA * DENSE_F + c);
#pragma unroll
        for (int j = 0; j < 8; ++j) {
            float fA = (float)vA[j];
            g0[j] = fmaf(wA, fA, g0[j]);
            m0[j] += fA;
        }
    }
    float inv = 1.0f / fmaxf((float)cnt[i], 1.0f);
    bf16x8 og, om;
#pragma unroll
    for (int j = 0; j < 8; ++j) {
        og[j] = (bf16_t)(g0[j] + g1[j]);
        om[j] = (bf16_t)((m0[j] + m1[j]) * inv);
    }
    *reinterpret_cast<bf16x8*>(gbf   + (long)i * HID + c) = og;
    *reinterpret_cast<bf16x8*>(meanb + (long)i * HID + c) = om;
}

// per-dst GAT attention over CSR (+self loop), softmax shift-free,
// hgat stride HG_LD=32 (3.85 MB, L2-resident), 4-edge unroll.
// 4 nodes per 256-thread block (one wave each).
__global__ __launch_bounds__(256) void gat_agg(
    const float* __restrict__ hgat, const int* __restrict__ rowptr,
    const int* __restrict__ col, const float* __restrict__ asrc,
    const float* __restrict__ adst, const float* __restrict__ b1p,
    const float* __restrict__ b2p, float* __restrict__ xout)
{
    int i = blockIdx.x * 4 + (threadIdx.x >> 6);
    int lane = threadIdx.x & 63;
    int h = (lane < NHEADS) ? lane : 0;
    float hg_i = hgat[(long)i * HG_LD + h];
    float as = asrc[h], ad = adst[h];
    float adhg = ad * hg_i;
    float ev = hg_i * as + adhg;
    ev = ev > 0.f ? ev : 0.2f * ev;
    float ex = __expf(ev);
    float den0 = ex, og0 = ex * hg_i, den1 = 0.f, og1 = 0.f;
    int e = rowptr[i], e1 = rowptr[i + 1];
    for (; e + 3 < e1; e += 4) {
        int sA = col[e], sB = col[e + 1], sC = col[e + 2], sD = col[e + 3];
        float hA = hgat[(long)sA * HG_LD + h];
        float hB = hgat[(long)sB * HG_LD + h];
        float hC = hgat[(long)sC * HG_LD + h];
        float hD = hgat[(long)sD * HG_LD + h];
        float tA = fmaf(hA, as, adhg); tA = tA > 0.f ? tA : 0.2f * tA;
        float tB = fmaf(hB, as, adhg); tB = tB > 0.f ? tB : 0.2f * tB;
        float tC = fmaf(hC, as, adhg); tC = tC > 0.f ? tC : 0.2f * tC;
        float tD = fmaf(hD, as, adhg); tD = tD > 0.f ? tD : 0.2f * tD;
        float xA = __expf(tA), xB = __expf(tB);
        float xC = __expf(tC), xD = __expf(tD);
        den0 += xA; og0 = fmaf(xA, hA, og0);
        den1 += xB; og1 = fmaf(xB, hB, og1);
        den0 += xC; og0 = fmaf(xC, hC, og0);
        den1 += xD; og1 = fmaf(xD, hD, og1);
    }
    for (; e < e1; ++e) {
        int sA = col[e];
        float hA = hgat[(long)sA * HG_LD + h];
        float tA = fmaf(hA, as, adhg); tA = tA > 0.f ? tA : 0.2f * tA;
        float xA = __expf(tA);
        den0 += xA; og0 = fmaf(xA, hA, og0);
    }
    float out = (lane < NHEADS) ? (og0 + og1) / (den0 + den1) : 0.f;
    float s4 = out + __shfl_xor(out, 1);
    s4 += __shfl_xor(s4, 2);
    float g0 = __shfl(s4, 0);
    float g1 = __shfl(s4, 4);
    float g2 = __shfl(s4, 8);
    float g3 = __shfl(s4, 12);
    float g4 = __shfl(s4, 16);
    if (lane == 0) {
        float a1 = g0 * 0.25f + b1p[0];
        float a2 = (g1 + g2 + g3 + g4) * 0.0625f + b2p[0];
        xout[i] = 0.5f * (a1 + a2);
    }
}

// ---------------------------------------------------------------------------
extern "C" void kernel_launch(void* const* d_in, const int* in_sizes, int n_in,
                              void* d_out, int out_size, void* d_ws, size_t ws_size,
                              hipStream_t stream) {
    (void)in_sizes; (void)n_in; (void)out_size; (void)ws_size;
    const float* x    = (const float*)d_in[0];
    const int*   ei   = (const int*)d_in[1];
    const float* ew   = (const float*)d_in[2];
    const float* W1   = (const float*)d_in[3];
    const float* b1   = (const float*)d_in[4];
    const float* W2   = (const float*)d_in[5];
    const float* b2   = (const float*)d_in[6];
    const float* sWl  = (const float*)d_in[7];
    const float* sWr  = (const float*)d_in[8];
    const float* sb   = (const float*)d_in[9];
    const float* g1W  = (const float*)d_in[10];
    const float* g1as = (const float*)d_in[11];
    const float* g1ad = (const float*)d_in[12];
    const float* g1b  = (const float*)d_in[13];
    const float* g2W  = (const float*)d_in[14];
    const float* g2as = (const float*)d_in[15];
    const float* g2ad = (const float*)d_in[16];
    const float* g2b  = (const float*)d_in[17];

    const int* src = ei;
    const int* dst = ei + N_EDGES;

    float* xout  = (float*)d_out;          // [N]
    float* dense = xout + N_NODES;         // [N,1536] fp32 (output 2)

    size_t off = 0;
    auto alloc = [&](size_t nbytes) -> void* {
        void* p = (char*)d_ws + off;
        off += (nbytes + 255) & ~(size_t)255;
        return p;
    };
    bf16_t* dense_bf = (bf16_t*)alloc((size_t)M_PAD * DENSE_F * 2);
    bf16_t* x_bf     = (bf16_t*)alloc((size_t)M_PAD * K1 * 2);
    bf16_t* aggx_bf  = (bf16_t*)alloc((size_t)M_PAD * K1 * 2);
    bf16_t* g_bf     = (bf16_t*)alloc((size_t)M_PAD * HID * 2);
    bf16_t* mean_bf  = (bf16_t*)alloc((size_t)M_PAD * HID * 2);
    float*  hgat     = (float*)alloc((size_t)M_PAD * HG_LD * 4);
    bf16_t* W1t      = (bf16_t*)alloc((size_t)512 * K1 * 2);
    bf16_t* W2t      = (bf16_t*)alloc((size_t)512 * 512 * 2);
    bf16_t* Bst      = (bf16_t*)alloc((size_t)512 * 1024 * 2);
    bf16_t* Wgt      = (bf16_t*)alloc((size_t)128 * DENSE_F * 2);
    float*  deg      = (float*)alloc((size_t)N_NODES * 4);
    float*  dinv     = (float*)alloc((size_t)N_NODES * 4);
    float*  asrc     = (float*)alloc(32 * 4);
    float*  adst     = (float*)alloc(32 * 4);
    int*    cnt      = (int*)alloc((size_t)N_NODES * 4);
    int*    rowp     = (int*)alloc((size_t)(N_NODES + 1) * 4);
    int*    woff     = (int*)alloc((size_t)N_NODES * 4);
    int*    colx     = (int*)alloc((size_t)N_EDGES * 4);
    float*  wcsr     = (float*)alloc((size_t)N_EDGES * 4);

    const int EB = EB_BLOCKS;

    hipMemsetAsync(deg, 0, (size_t)N_NODES * 4, stream);
    hipMemsetAsync(cnt, 0, (size_t)N_NODES * 4, stream);

    // Fused: build_stats || conv_x || pack_weights
    prologue<<<PRO_BLOCKS, 256, 0, stream>>>(
        dst, ew, deg, cnt, x, x_bf,
        W1, W2, sWl, sWr, g1W, g2W, g1as, g1ad, g2as, g2ad,
        W1t, W2t, Bst, Wgt, asrc, adst);
    // Fused: exclusive scan + node_stats (deg+1, rsqrt)
    scan_rowptr_fast<<<1, 1024, 0, stream>>>(cnt, rowp, woff, deg, dinv);
    scatter_csr<<<EB, 256, 0, stream>>>(src, dst, ew, woff, colx, wcsr);

    const dim3 gB(256);
    const dim3 g512(HID / 128, M_PAD / 128);      // (4, 235)
    const dim3 gdual(8, M_PAD / 128);             // (8, 235): GCN2 + SAGE
    const dim3 g128(1, M_PAD / 128);              // (1, 235): GAT

    // GCN1 (commuted): aggx = A_gcn * x ; x1 = relu(aggx@W1 + b1) -> dense[:,0:512]
    agg_x<<<N_NODES / 4, 256, 0, stream>>>(x_bf, rowp, colx, wcsr, dinv, deg, aggx_bf);
    gemm_bf16<<<g512, gB, 0, stream>>>(aggx_bf, K1, K1, aggx_bf, K1, W1t, K1,
                                       dense, dense_bf, DENSE_F, K1, b1, 512);

    // Fused x1 gather: g = A_gcn * x1 (GCN2), mean = mean(x1) (SAGE)
    agg_x1<<<N_NODES / 4, 256, 0, stream>>>(dense_bf, rowp, colx, wcsr, dinv, deg, cnt,
                                            g_bf, mean_bf);
    // GCN2 + SAGE fused into one launch (independent GEMMs):
    //   x2 = relu(g@W2 + b2)                 -> dense[:,512:1024]
    //   x3 = relu([mean|x1]@[Wl;Wr] + sb)    -> dense[:,1024:1536]
    gemm_bf16_dual<<<gdual, gB, 0, stream>>>(
        g_bf, HID, HID, g_bf, HID, W2t, HID,
        dense + HID, dense_bf + HID, DENSE_F, HID, b2, 512,
        mean_bf, HID, HID, dense_bf, DENSE_F, Bst, 1024,
        dense + 2 * HID, dense_bf + 2 * HID, DENSE_F, 1024, sb, 512);

    // GAT: hgat = dense @ Wg (fp32, masked to 32 cols, stride 32), then aggregate
    gemm_bf16<<<g128, gB, 0, stream>>>(dense_bf, DENSE_F, DENSE_F, dense_bf, DENSE_F,
                                       Wgt, DENSE_F, hgat, nullptr, HG_LD,
                                       DENSE_F, nullptr, HG_LD);
    gat_agg<<<N_NODES / 4, 256, 0, stream>>>(hgat, rowp, colx, asrc, adst, g1b, g2b, xout);
}

// Round 5
// 763.525 us; speedup vs baseline: 1.0971x; 1.0724x over previous
//
#include <hip/hip_runtime.h>
#include <hip/hip_bf16.h>
#include <stdint.h>

#define N_NODES 30000
#define M_PAD   30080      // 235 * 128, GEMM M padding
#define N_EDGES 480000
#define F_IN 376
#define K1   384           // F_IN padded to BK multiple
#define HID 512
#define DENSE_F 1536
#define NHEADS 20          // 4 (gat1) + 16 (gat2)
#define HG_LD 32           // hgat leading dim (fp32): 3.85 MB, L2-resident

typedef __bf16 bf16_t;
typedef bf16_t bf16x8 __attribute__((ext_vector_type(8)));
typedef float  f32x4  __attribute__((ext_vector_type(4)));

#define S1 (512 * K1)
#define S2 (512 * 512)
#define S3 (512 * 1024)
#define S4 (128 * DENSE_F)
#define PW_ELEMS (S1 + S2 + S3 + S4 + NHEADS)

#define EB_BLOCKS ((N_EDGES + 255) / 256)
#define CX_BLOCKS ((M_PAD * K1) / 256)           // 45120 exactly
#define PW_BLOCKS ((PW_ELEMS + 255) / 256)
#define PRO_BLOCKS (EB_BLOCKS + CX_BLOCKS + PW_BLOCKS)

// ---------------------------------------------------------------------------
// Fused prologue: three independent stages run concurrently in one launch.
// ---------------------------------------------------------------------------
__global__ __launch_bounds__(256) void prologue(
    const int* __restrict__ dst, const float* __restrict__ ew,
    float* __restrict__ deg, int* __restrict__ cnt,
    const float* __restrict__ x, bf16_t* __restrict__ xb,
    const float* __restrict__ W1, const float* __restrict__ W2,
    const float* __restrict__ Wl, const float* __restrict__ Wr,
    const float* __restrict__ g1W, const float* __restrict__ g2W,
    const float* __restrict__ a1s, const float* __restrict__ a1d,
    const float* __restrict__ a2s, const float* __restrict__ a2d,
    bf16_t* __restrict__ W1t, bf16_t* __restrict__ W2t,
    bf16_t* __restrict__ Bst, bf16_t* __restrict__ Wgt,
    float* __restrict__ asrc, float* __restrict__ adst)
{
    int b = blockIdx.x;
    if (b < EB_BLOCKS) {
        int e = b * 256 + threadIdx.x;
        if (e >= N_EDGES) return;
        int t = dst[e];
        atomicAdd(&deg[t], ew[e]);
        atomicAdd(&cnt[t], 1);
    } else if (b < EB_BLOCKS + CX_BLOCKS) {
        int tid = (b - EB_BLOCKS) * 256 + threadIdx.x;
        int r = tid / K1, c = tid - r * K1;
        float v = (r < N_NODES && c < F_IN) ? x[r * F_IN + c] : 0.f;
        xb[tid] = (bf16_t)v;
    } else {
        int tid = (b - EB_BLOCKS - CX_BLOCKS) * 256 + threadIdx.x;
        if (tid < S1) {
            int n = tid / K1, k = tid - n * K1;
            W1t[tid] = (bf16_t)((k < F_IN) ? W1[k * HID + n] : 0.f);
        } else if (tid < S1 + S2) {
            int t = tid - S1;
            int n = t >> 9, k = t & 511;
            W2t[t] = (bf16_t)W2[k * HID + n];
        } else if (tid < S1 + S2 + S3) {
            int t = tid - S1 - S2;
            int n = t >> 10, k = t & 1023;
            Bst[t] = (bf16_t)((k < HID) ? Wl[k * HID + n] : Wr[(k - HID) * HID + n]);
        } else if (tid < S1 + S2 + S3 + S4) {
            int t = tid - S1 - S2 - S3;
            int n = t / DENSE_F, k = t - n * DENSE_F;
            float v = (n < 4) ? g1W[k * 4 + n] : (n < NHEADS) ? g2W[k * 16 + (n - 4)] : 0.f;
            Wgt[t] = (bf16_t)v;
        } else if (tid < S1 + S2 + S3 + S4 + NHEADS) {
            int hh = tid - S1 - S2 - S3 - S4;
            asrc[hh] = (hh < 4) ? a1s[hh] : a2s[hh - 4];
            adst[hh] = (hh < 4) ? a1d[hh] : a2d[hh - 4];
        }
    }
}

// ---------------------------------------------------------------------------
// Fast exclusive scan of cnt -> rowptr/woff, + node_stats fold (deg+1, rsqrt).
// ---------------------------------------------------------------------------
#define SEG 30
__global__ __launch_bounds__(1024) void scan_rowptr_fast(
    const int* __restrict__ cnt, int* __restrict__ rowptr, int* __restrict__ woff,
    float* __restrict__ deg, float* __restrict__ dinv)
{
    int t = threadIdx.x;
    int base = t * SEG;
    int v[SEG];
    int sum = 0;
#pragma unroll
    for (int j = 0; j < SEG; ++j) {
        int i = base + j;
        int c = (i < N_NODES) ? cnt[i] : 0;
        v[j] = c;
        sum += c;
        if (i < N_NODES) {
            float d = deg[i] + 1.0f;   // self-loop weight 1
            deg[i] = d;
            dinv[i] = rsqrtf(d);
        }
    }
    int lane = t & 63;
    int wid = t >> 6;
    int s = sum;
#pragma unroll
    for (int off = 1; off < 64; off <<= 1) {
        int u = __shfl_up(s, off);
        if (lane >= off) s += u;
    }
    __shared__ int wsum[16];
    if (lane == 63) wsum[wid] = s;
    __syncthreads();
    if (t < 16) {
        int ws = wsum[t];
#pragma unroll
        for (int off = 1; off < 16; off <<= 1) {
            int u = __shfl_up(ws, off);
            if (t >= off) ws += u;
        }
        wsum[t] = ws;
    }
    __syncthreads();
    int carry = (wid > 0) ? wsum[wid - 1] : 0;
    int excl = carry + s - sum;   // exclusive prefix for this thread's segment
#pragma unroll
    for (int j = 0; j < SEG; ++j) {
        int i = base + j;
        if (i < N_NODES) { rowptr[i] = excl; woff[i] = excl; }
        excl += v[j];
    }
    if (t == 1023) rowptr[N_NODES] = excl;   // total edge count
}

__global__ __launch_bounds__(256) void scatter_csr(
    const int* __restrict__ src, const int* __restrict__ dst,
    const float* __restrict__ ew, int* __restrict__ woff,
    int* __restrict__ col, float* __restrict__ wcsr)
{
    int e = blockIdx.x * 256 + threadIdx.x;
    if (e >= N_EDGES) return;
    int t = dst[e];
    int p = atomicAdd(&woff[t], 1);
    col[p] = src[e];
    wcsr[p] = ew[e];
}

// ---------------------------------------------------------------------------
// Bijective XCD remap (m204): hardware block d -> logical l so each XCD gets
// a CONTIGUOUS run of logical ids. Then x = l % gx shares the A-row panel and
// the whole B matrix within one XCD's L2.
// ---------------------------------------------------------------------------
__device__ __forceinline__ void xcd_remap(int nwg, int gx, int& bx, int& by)
{
    int d = blockIdx.x;
    int xcd = d & 7, pos = d >> 3;
    int q = nwg >> 3, r = nwg & 7;
    int l = (xcd < r ? xcd * (q + 1) : r * (q + 1) + (xcd - r) * q) + pos;
    bx = l % gx;
    by = l / gx;
}

// ---------------------------------------------------------------------------
// bf16 MFMA GEMM (NT) body, 3-buffer 2-deep pipeline (T3+T4):
//   prologue: stage(0), stage(1)                       [8 loads in flight]
//   step s:   stage((s+2)%3)                           [12 in flight]
//             s_waitcnt vmcnt(8)   <- step-s loads done; s+1,s+2 IN FLIGHT
//             s_barrier            <- raw: does NOT drain vmcnt
//             ds_read buf[s%3] + MFMA (compiler inserts lgkmcnt)
//             s_barrier            <- reads done before buf reuse next step
// Tail: vmcnt(4) at s==nsteps-2, vmcnt(0) at s==nsteps-1. Requires nsteps>=2.
// Race audit: barrier1 follows each wave's own vmcnt wait -> buf fully staged;
// barrier2 follows lgkm-drained reads -> safe overwrite at step s+1.
// ---------------------------------------------------------------------------
#define BUF_E (128 * 32)
__device__ __forceinline__ void gemm_body(
    const bf16_t* __restrict__ A1, int lda1, int ksplit,
    const bf16_t* __restrict__ A2, int lda2,
    const bf16_t* __restrict__ Bt, int ldb,
    float* __restrict__ C, bf16_t* __restrict__ Cb, long ldc, int K,
    const float* __restrict__ bias, int ncols,
    int n0, long r0, bf16_t* smem)
{
    const int tid = threadIdx.x;
    const int wid = tid >> 6, lane = tid & 63;
    const int li = lane & 15, kq = lane >> 4;
    const int wm = (wid >> 1) * 64, wn = (wid & 1) * 64;

    f32x4 acc[4][4] = {};

    const int s0 = wid * 64 + lane;
    const int s1 = 256 + s0;
    const int am0 = s0 >> 2, ak0 = (s0 & 3) ^ ((am0 >> 1) & 3);
    const int am1 = s1 >> 2, ak1 = (s1 & 3) ^ ((am1 >> 1) & 3);
    const int swz = (li >> 1) & 3;

    auto stage = [&](int buf, int k0) {
        const bf16_t* Ab; int lda;
        if (k0 < ksplit) { Ab = A1 + k0;            lda = lda1; }
        else             { Ab = A2 + (k0 - ksplit); lda = lda2; }
        bf16_t* Asb = smem + buf * (2 * BUF_E);
        bf16_t* Bsb = Asb + BUF_E;
        __builtin_amdgcn_global_load_lds(
            (const __attribute__((address_space(1))) void*)(Ab + (r0 + am0) * (long)lda + ak0 * 8),
            (__attribute__((address_space(3))) void*)(Asb + (wid * 64) * 8), 16, 0, 0);
        __builtin_amdgcn_global_load_lds(
            (const __attribute__((address_space(1))) void*)(Ab + (r0 + am1) * (long)lda + ak1 * 8),
            (__attribute__((address_space(3))) void*)(Asb + (256 + wid * 64) * 8), 16, 0, 0);
        __builtin_amdgcn_global_load_lds(
            (const __attribute__((address_space(1))) void*)(Bt + (n0 + am0) * (long)ldb + k0 + ak0 * 8),
            (__attribute__((address_space(3))) void*)(Bsb + (wid * 64) * 8), 16, 0, 0);
        __builtin_amdgcn_global_load_lds(
            (const __attribute__((address_space(1))) void*)(Bt + (n0 + am1) * (long)ldb + k0 + ak1 * 8),
            (__attribute__((address_space(3))) void*)(Bsb + (256 + wid * 64) * 8), 16, 0, 0);
    };

    const int nsteps = K >> 5;     // all call sites have nsteps >= 12
    stage(0, 0);
    stage(1, 32);

    int cur = 0, nx2 = 2;
    for (int s = 0; s < nsteps; ++s) {
        if (s + 2 < nsteps) {
            stage(nx2, (s + 2) << 5);
            asm volatile("s_waitcnt vmcnt(8)" ::: "memory");
        } else if (s + 2 == nsteps) {
            asm volatile("s_waitcnt vmcnt(4)" ::: "memory");
        } else {
            asm volatile("s_waitcnt vmcnt(0)" ::: "memory");
        }
        __builtin_amdgcn_s_barrier();          // buf[cur] fully staged (all waves)
        __builtin_amdgcn_sched_barrier(0);

        const bf16_t* Asb = smem + cur * (2 * BUF_E);
        const bf16_t* Bsb = Asb + BUF_E;
        bf16x8 a[4], b[4];
#pragma unroll
        for (int f = 0; f < 4; ++f) {
            int m = wm + f * 16 + li;
            a[f] = *(const bf16x8*)(Asb + m * 32 + ((kq ^ swz) * 8));
            int n = wn + f * 16 + li;
            b[f] = *(const bf16x8*)(Bsb + n * 32 + ((kq ^ swz) * 8));
        }
#pragma unroll
        for (int fm = 0; fm < 4; ++fm)
#pragma unroll
            for (int fn = 0; fn < 4; ++fn)
                acc[fm][fn] = __builtin_amdgcn_mfma_f32_16x16x32_bf16(
                    a[fm], b[fn], acc[fm][fn], 0, 0, 0);

        __builtin_amdgcn_sched_barrier(0);
        __builtin_amdgcn_s_barrier();          // reads done before buf reuse
        __builtin_amdgcn_sched_barrier(0);

        cur = (cur == 2) ? 0 : cur + 1;
        nx2 = (nx2 == 2) ? 0 : nx2 + 1;
    }

    // C/D layout: col = lane&15, row = (lane>>4)*4 + reg
#pragma unroll
    for (int fm = 0; fm < 4; ++fm) {
#pragma unroll
        for (int r = 0; r < 4; ++r) {
            long row = r0 + wm + fm * 16 + kq * 4 + r;
            if (row >= N_NODES) continue;
#pragma unroll
            for (int fn = 0; fn < 4; ++fn) {
                int colg = n0 + wn + fn * 16 + li;
                if (colg >= ncols) continue;
                float v = acc[fm][fn][r];
                if (bias) v = fmaxf(v + bias[colg], 0.f);
                if (C)  C[row * ldc + colg]  = v;
                if (Cb) Cb[row * ldc + colg] = (bf16_t)v;
            }
        }
    }
}

// 1D grid; gx = tiles along N. XCD-swizzled decode.
__global__ __launch_bounds__(256) void gemm_bf16(
    const bf16_t* __restrict__ A1, int lda1, int ksplit,
    const bf16_t* __restrict__ A2, int lda2,
    const bf16_t* __restrict__ Bt, int ldb,
    float* __restrict__ C, bf16_t* __restrict__ Cb, long ldc, int K,
    const float* __restrict__ bias, int ncols, int gx)
{
    __shared__ bf16_t smem[3 * 2 * BUF_E];
    int bx, by;
    xcd_remap((int)gridDim.x, gx, bx, by);
    gemm_body(A1, lda1, ksplit, A2, lda2, Bt, ldb, C, Cb, ldc, K, bias, ncols,
              bx * 128, (long)by * 128, smem);
}

// Two independent GEMMs (GCN2 + SAGE) in one launch: bx<4 -> set 0.
__global__ __launch_bounds__(256) void gemm_bf16_dual(
    const bf16_t* __restrict__ A1a, int lda1a, int ksplita,
    const bf16_t* __restrict__ A2a, int lda2a,
    const bf16_t* __restrict__ Bta, int ldba,
    float* __restrict__ Ca, bf16_t* __restrict__ Cba, long ldca, int Ka,
    const float* __restrict__ biasa, int ncolsa,
    const bf16_t* __restrict__ A1b, int lda1b, int ksplitb,
    const bf16_t* __restrict__ A2b, int lda2b,
    const bf16_t* __restrict__ Btb, int ldbb,
    float* __restrict__ Cb2, bf16_t* __restrict__ Cbb, long ldcb, int Kb,
    const float* __restrict__ biasb, int ncolsb)
{
    __shared__ bf16_t smem[3 * 2 * BUF_E];
    int bx, by;
    xcd_remap((int)gridDim.x, 8, bx, by);
    long r0 = (long)by * 128;
    if (bx < 4) {
        gemm_body(A1a, lda1a, ksplita, A2a, lda2a, Bta, ldba, Ca, Cba, ldca, Ka,
                  biasa, ncolsa, bx * 128, r0, smem);
    } else {
        gemm_body(A1b, lda1b, ksplitb, A2b, lda2b, Btb, ldbb, Cb2, Cbb, ldcb, Kb,
                  biasb, ncolsb, (bx - 4) * 128, r0, smem);
    }
}

// ---------------------------------------------------------------------------
// GCN aggregation over raw x_bf (384 cols): aggx[i] = x[i]/deg + sum norm*x[s]
// 4 nodes per 256-thread block (one wave each); 4-edge unroll for MLP.
// ---------------------------------------------------------------------------
__global__ __launch_bounds__(256) void agg_x(
    const bf16_t* __restrict__ xb, const int* __restrict__ rowptr,
    const int* __restrict__ col, const float* __restrict__ wcsr,
    const float* __restrict__ dinv, const float* __restrict__ deg,
    bf16_t* __restrict__ aggx)
{
    int i = blockIdx.x * 4 + (threadIdx.x >> 6);
    int lane = threadIdx.x & 63;
    int c = lane * 8;
    bool act = (c < K1);
    float di = dinv[i];
    float selfw = 1.0f / deg[i];
    float acc0[8] = {}, acc1[8] = {};
    if (act) {
        bf16x8 sv = *(const bf16x8*)(xb + (long)i * K1 + c);
#pragma unroll
        for (int j = 0; j < 8; ++j) acc0[j] = selfw * (float)sv[j];
    }
    int e = rowptr[i], e1 = rowptr[i + 1];
    for (; e + 3 < e1; e += 4) {
        int sA = col[e], sB = col[e + 1], sC = col[e + 2], sD = col[e + 3];
        float wA = dinv[sA] * wcsr[e]     * di;
        float wB = dinv[sB] * wcsr[e + 1] * di;
        float wC = dinv[sC] * wcsr[e + 2] * di;
        float wD = dinv[sD] * wcsr[e + 3] * di;
        if (act) {
            bf16x8 vA = *(const bf16x8*)(xb + (long)sA * K1 + c);
            bf16x8 vB = *(const bf16x8*)(xb + (long)sB * K1 + c);
            bf16x8 vC = *(const bf16x8*)(xb + (long)sC * K1 + c);
            bf16x8 vD = *(const bf16x8*)(xb + (long)sD * K1 + c);
#pragma unroll
            for (int j = 0; j < 8; ++j) {
                acc0[j] = fmaf(wA, (float)vA[j], acc0[j]);
                acc1[j] = fmaf(wB, (float)vB[j], acc1[j]);
                acc0[j] = fmaf(wC, (float)vC[j], acc0[j]);
                acc1[j] = fmaf(wD, (float)vD[j], acc1[j]);
            }
        }
    }
    for (; e < e1; ++e) {
        int sA = col[e];
        float wA = dinv[sA] * wcsr[e] * di;
        if (act) {
            bf16x8 vA = *(const bf16x8*)(xb + (long)sA * K1 + c);
#pragma unroll
            for (int j = 0; j < 8; ++j) acc0[j] = fmaf(wA, (float)vA[j], acc0[j]);
        }
    }
    if (act) {
        bf16x8 ob;
#pragma unroll
        for (int j = 0; j < 8; ++j) ob[j] = (bf16_t)(acc0[j] + acc1[j]);
        *reinterpret_cast<bf16x8*>(aggx + (long)i * K1 + c) = ob;
    }
}

// ---------------------------------------------------------------------------
// Fused x1 aggregation: ONE gather of x1 rows serves GCN2 (norm-weighted sum
// + self) AND SAGE (plain mean). 4 nodes/block, 4-edge unroll.
// ---------------------------------------------------------------------------
__global__ __launch_bounds__(256) void agg_x1(
    const bf16_t* __restrict__ x1b /* dense_bf, cols [0,512) */,
    const int* __restrict__ rowptr, const int* __restrict__ col,
    const float* __restrict__ wcsr, const float* __restrict__ dinv,
    const float* __restrict__ deg, const int* __restrict__ cnt,
    bf16_t* __restrict__ gbf, bf16_t* __restrict__ meanb)
{
    int i = blockIdx.x * 4 + (threadIdx.x >> 6);
    int lane = threadIdx.x & 63;
    int c = lane * 8;
    float di = dinv[i];
    float selfw = 1.0f / deg[i];
    bf16x8 sv = *(const bf16x8*)(x1b + (long)i * DENSE_F + c);
    float g0[8], g1[8], m0[8], m1[8];
#pragma unroll
    for (int j = 0; j < 8; ++j) {
        g0[j] = selfw * (float)sv[j];
        g1[j] = 0.f; m0[j] = 0.f; m1[j] = 0.f;
    }
    int e = rowptr[i], e1 = rowptr[i + 1];
    for (; e + 3 < e1; e += 4) {
        int sA = col[e], sB = col[e + 1], sC = col[e + 2], sD = col[e + 3];
        float wA = dinv[sA] * wcsr[e]     * di;
        float wB = dinv[sB] * wcsr[e + 1] * di;
        float wC = dinv[sC] * wcsr[e + 2] * di;
        float wD = dinv[sD] * wcsr[e + 3] * di;
        bf16x8 vA = *(const bf16x8*)(x1b + (long)sA * DENSE_F + c);
        bf16x8 vB = *(const bf16x8*)(x1b + (long)sB * DENSE_F + c);
        bf16x8 vC = *(const bf16x8*)(x1b + (long)sC * DENSE_F + c);
        bf16x8 vD = *(const bf16x8*)(x1b + (long)sD * DENSE_F + c);
#pragma unroll
        for (int j = 0; j < 8; ++j) {
            float fA = (float)vA[j], fB = (float)vB[j];
            float fC = (float)vC[j], fD = (float)vD[j];
            g0[j] = fmaf(wA, fA, g0[j]);
            g1[j] = fmaf(wB, fB, g1[j]);
            g0[j] = fmaf(wC, fC, g0[j]);
            g1[j] = fmaf(wD, fD, g1[j]);
            m0[j] += fA + fC;
            m1[j] += fB + fD;
        }
    }
    for (; e < e1; ++e) {
        int sA = col[e];
        float wA = dinv[sA] * wcsr[e] * di;
        bf16x8 vA = *(const bf16x8*)(x1b + (long)sA * DENSE_F + c);
#pragma unroll
        for (int j = 0; j < 8; ++j) {
            float fA = (float)vA[j];
            g0[j] = fmaf(wA, fA, g0[j]);
            m0[j] += fA;
        }
    }
    float inv = 1.0f / fmaxf((float)cnt[i], 1.0f);
    bf16x8 og, om;
#pragma unroll
    for (int j = 0; j < 8; ++j) {
        og[j] = (bf16_t)(g0[j] + g1[j]);
        om[j] = (bf16_t)((m0[j] + m1[j]) * inv);
    }
    *reinterpret_cast<bf16x8*>(gbf   + (long)i * HID + c) = og;
    *reinterpret_cast<bf16x8*>(meanb + (long)i * HID + c) = om;
}

// per-dst GAT attention over CSR (+self loop), softmax shift-free,
// hgat stride HG_LD=32 (3.85 MB, L2-resident), 4-edge unroll.
// 4 nodes per 256-thread block (one wave each).
__global__ __launch_bounds__(256) void gat_agg(
    const float* __restrict__ hgat, const int* __restrict__ rowptr,
    const int* __restrict__ col, const float* __restrict__ asrc,
    const float* __restrict__ adst, const float* __restrict__ b1p,
    const float* __restrict__ b2p, float* __restrict__ xout)
{
    int i = blockIdx.x * 4 + (threadIdx.x >> 6);
    int lane = threadIdx.x & 63;
    int h = (lane < NHEADS) ? lane : 0;
    float hg_i = hgat[(long)i * HG_LD + h];
    float as = asrc[h], ad = adst[h];
    float adhg = ad * hg_i;
    float ev = hg_i * as + adhg;
    ev = ev > 0.f ? ev : 0.2f * ev;
    float ex = __expf(ev);
    float den0 = ex, og0 = ex * hg_i, den1 = 0.f, og1 = 0.f;
    int e = rowptr[i], e1 = rowptr[i + 1];
    for (; e + 3 < e1; e += 4) {
        int sA = col[e], sB = col[e + 1], sC = col[e + 2], sD = col[e + 3];
        float hA = hgat[(long)sA * HG_LD + h];
        float hB = hgat[(long)sB * HG_LD + h];
        float hC = hgat[(long)sC * HG_LD + h];
        float hD = hgat[(long)sD * HG_LD + h];
        float tA = fmaf(hA, as, adhg); tA = tA > 0.f ? tA : 0.2f * tA;
        float tB = fmaf(hB, as, adhg); tB = tB > 0.f ? tB : 0.2f * tB;
        float tC = fmaf(hC, as, adhg); tC = tC > 0.f ? tC : 0.2f * tC;
        float tD = fmaf(hD, as, adhg); tD = tD > 0.f ? tD : 0.2f * tD;
        float xA = __expf(tA), xB = __expf(tB);
        float xC = __expf(tC), xD = __expf(tD);
        den0 += xA; og0 = fmaf(xA, hA, og0);
        den1 += xB; og1 = fmaf(xB, hB, og1);
        den0 += xC; og0 = fmaf(xC, hC, og0);
        den1 += xD; og1 = fmaf(xD, hD, og1);
    }
    for (; e < e1; ++e) {
        int sA = col[e];
        float hA = hgat[(long)sA * HG_LD + h];
        float tA = fmaf(hA, as, adhg); tA = tA > 0.f ? tA : 0.2f * tA;
        float xA = __expf(tA);
        den0 += xA; og0 = fmaf(xA, hA, og0);
    }
    float out = (lane < NHEADS) ? (og0 + og1) / (den0 + den1) : 0.f;
    float s4 = out + __shfl_xor(out, 1);
    s4 += __shfl_xor(s4, 2);
    float g0 = __shfl(s4, 0);
    float g1 = __shfl(s4, 4);
    float g2 = __shfl(s4, 8);
    float g3 = __shfl(s4, 12);
    float g4 = __shfl(s4, 16);
    if (lane == 0) {
        float a1 = g0 * 0.25f + b1p[0];
        float a2 = (g1 + g2 + g3 + g4) * 0.0625f + b2p[0];
        xout[i] = 0.5f * (a1 + a2);
    }
}

// ---------------------------------------------------------------------------
extern "C" void kernel_launch(void* const* d_in, const int* in_sizes, int n_in,
                              void* d_out, int out_size, void* d_ws, size_t ws_size,
                              hipStream_t stream) {
    (void)in_sizes; (void)n_in; (void)out_size; (void)ws_size;
    const float* x    = (const float*)d_in[0];
    const int*   ei   = (const int*)d_in[1];
    const float* ew   = (const float*)d_in[2];
    const float* W1   = (const float*)d_in[3];
    const float* b1   = (const float*)d_in[4];
    const float* W2   = (const float*)d_in[5];
    const float* b2   = (const float*)d_in[6];
    const float* sWl  = (const float*)d_in[7];
    const float* sWr  = (const float*)d_in[8];
    const float* sb   = (const float*)d_in[9];
    const float* g1W  = (const float*)d_in[10];
    const float* g1as = (const float*)d_in[11];
    const float* g1ad = (const float*)d_in[12];
    const float* g1b  = (const float*)d_in[13];
    const float* g2W  = (const float*)d_in[14];
    const float* g2as = (const float*)d_in[15];
    const float* g2ad = (const float*)d_in[16];
    const float* g2b  = (const float*)d_in[17];

    const int* src = ei;
    const int* dst = ei + N_EDGES;

    float* xout  = (float*)d_out;          // [N]
    float* dense = xout + N_NODES;         // [N,1536] fp32 (output 2)

    size_t off = 0;
    auto alloc = [&](size_t nbytes) -> void* {
        void* p = (char*)d_ws + off;
        off += (nbytes + 255) & ~(size_t)255;
        return p;
    };
    bf16_t* dense_bf = (bf16_t*)alloc((size_t)M_PAD * DENSE_F * 2);
    bf16_t* x_bf     = (bf16_t*)alloc((size_t)M_PAD * K1 * 2);
    bf16_t* aggx_bf  = (bf16_t*)alloc((size_t)M_PAD * K1 * 2);
    bf16_t* g_bf     = (bf16_t*)alloc((size_t)M_PAD * HID * 2);
    bf16_t* mean_bf  = (bf16_t*)alloc((size_t)M_PAD * HID * 2);
    float*  hgat     = (float*)alloc((size_t)M_PAD * HG_LD * 4);
    bf16_t* W1t      = (bf16_t*)alloc((size_t)512 * K1 * 2);
    bf16_t* W2t      = (bf16_t*)alloc((size_t)512 * 512 * 2);
    bf16_t* Bst      = (bf16_t*)alloc((size_t)512 * 1024 * 2);
    bf16_t* Wgt      = (bf16_t*)alloc((size_t)128 * DENSE_F * 2);
    float*  deg      = (float*)alloc((size_t)N_NODES * 4);
    float*  dinv     = (float*)alloc((size_t)N_NODES * 4);
    float*  asrc     = (float*)alloc(32 * 4);
    float*  adst     = (float*)alloc(32 * 4);
    int*    cnt      = (int*)alloc((size_t)N_NODES * 4);
    int*    rowp     = (int*)alloc((size_t)(N_NODES + 1) * 4);
    int*    woff     = (int*)alloc((size_t)N_NODES * 4);
    int*    colx     = (int*)alloc((size_t)N_EDGES * 4);
    float*  wcsr     = (float*)alloc((size_t)N_EDGES * 4);

    const int EB = EB_BLOCKS;

    hipMemsetAsync(deg, 0, (size_t)N_NODES * 4, stream);
    hipMemsetAsync(cnt, 0, (size_t)N_NODES * 4, stream);

    // Fused: build_stats || conv_x || pack_weights
    prologue<<<PRO_BLOCKS, 256, 0, stream>>>(
        dst, ew, deg, cnt, x, x_bf,
        W1, W2, sWl, sWr, g1W, g2W, g1as, g1ad, g2as, g2ad,
        W1t, W2t, Bst, Wgt, asrc, adst);
    // Fused: exclusive scan + node_stats (deg+1, rsqrt)
    scan_rowptr_fast<<<1, 1024, 0, stream>>>(cnt, rowp, woff, deg, dinv);
    scatter_csr<<<EB, 256, 0, stream>>>(src, dst, ew, woff, colx, wcsr);

    const dim3 gB(256);
    const int NT = M_PAD / 128;                   // 235 row tiles

    // GCN1 (commuted): aggx = A_gcn * x ; x1 = relu(aggx@W1 + b1) -> dense[:,0:512]
    agg_x<<<N_NODES / 4, 256, 0, stream>>>(x_bf, rowp, colx, wcsr, dinv, deg, aggx_bf);
    gemm_bf16<<<4 * NT, gB, 0, stream>>>(aggx_bf, K1, K1, aggx_bf, K1, W1t, K1,
                                         dense, dense_bf, DENSE_F, K1, b1, 512, 4);

    // Fused x1 gather: g = A_gcn * x1 (GCN2), mean = mean(x1) (SAGE)
    agg_x1<<<N_NODES / 4, 256, 0, stream>>>(dense_bf, rowp, colx, wcsr, dinv, deg, cnt,
                                            g_bf, mean_bf);
    // GCN2 + SAGE fused into one launch (independent GEMMs):
    //   x2 = relu(g@W2 + b2)                 -> dense[:,512:1024]
    //   x3 = relu([mean|x1]@[Wl;Wr] + sb)    -> dense[:,1024:1536]
    gemm_bf16_dual<<<8 * NT, gB, 0, stream>>>(
        g_bf, HID, HID, g_bf, HID, W2t, HID,
        dense + HID, dense_bf + HID, DENSE_F, HID, b2, 512,
        mean_bf, HID, HID, dense_bf, DENSE_F, Bst, 1024,
        dense + 2 * HID, dense_bf + 2 * HID, DENSE_F, 1024, sb, 512);

    // GAT: hgat = dense @ Wg (fp32, masked to 32 cols, stride 32), then aggregate
    gemm_bf16<<<1 * NT, gB, 0, stream>>>(dense_bf, DENSE_F, DENSE_F, dense_bf, DENSE_F,
                                         Wgt, DENSE_F, hgat, nullptr, HG_LD,
                                         DENSE_F, nullptr, HG_LD, 1);
    gat_agg<<<N_NODES / 4, 256, 0, stream>>>(hgat, rowp, colx, asrc, adst, g1b, g2b, xout);
}

// Round 6
// 761.529 us; speedup vs baseline: 1.1000x; 1.0026x over previous
//
#include <hip/hip_runtime.h>
#include <hip/hip_bf16.h>
#include <stdint.h>

#define N_NODES 30000
#define M_PAD   30080      // 235 * 128, GEMM M padding
#define N_EDGES 480000
#define F_IN 376
#define K1   384           // F_IN padded to BK multiple
#define HID 512
#define DENSE_F 1536
#define NHEADS 20          // 4 (gat1) + 16 (gat2)
#define HG_LD 32           // hgat leading dim (fp32): 3.85 MB, L2-resident

typedef __bf16 bf16_t;
typedef bf16_t bf16x8 __attribute__((ext_vector_type(8)));
typedef float  f32x4  __attribute__((ext_vector_type(4)));

#define S1 (512 * K1)
#define S2 (512 * 512)
#define S3 (512 * 1024)
#define S4 (128 * DENSE_F)
#define PW_ELEMS (S1 + S2 + S3 + S4 + NHEADS)

#define EB_BLOCKS ((N_EDGES + 255) / 256)
#define CX_BLOCKS ((M_PAD * K1) / 256)           // 45120 exactly
#define PW_BLOCKS ((PW_ELEMS + 255) / 256)
#define PRO_BLOCKS (EB_BLOCKS + CX_BLOCKS + PW_BLOCKS)

// ---------------------------------------------------------------------------
// Fused prologue: three independent stages run concurrently in one launch.
// ---------------------------------------------------------------------------
__global__ __launch_bounds__(256) void prologue(
    const int* __restrict__ dst, const float* __restrict__ ew,
    float* __restrict__ deg, int* __restrict__ cnt,
    const float* __restrict__ x, bf16_t* __restrict__ xb,
    const float* __restrict__ W1, const float* __restrict__ W2,
    const float* __restrict__ Wl, const float* __restrict__ Wr,
    const float* __restrict__ g1W, const float* __restrict__ g2W,
    const float* __restrict__ a1s, const float* __restrict__ a1d,
    const float* __restrict__ a2s, const float* __restrict__ a2d,
    bf16_t* __restrict__ W1t, bf16_t* __restrict__ W2t,
    bf16_t* __restrict__ Bst, bf16_t* __restrict__ Wgt,
    float* __restrict__ asrc, float* __restrict__ adst)
{
    int b = blockIdx.x;
    if (b < EB_BLOCKS) {
        int e = b * 256 + threadIdx.x;
        if (e >= N_EDGES) return;
        int t = dst[e];
        atomicAdd(&deg[t], ew[e]);
        atomicAdd(&cnt[t], 1);
    } else if (b < EB_BLOCKS + CX_BLOCKS) {
        int tid = (b - EB_BLOCKS) * 256 + threadIdx.x;
        int r = tid / K1, c = tid - r * K1;
        float v = (r < N_NODES && c < F_IN) ? x[r * F_IN + c] : 0.f;
        xb[tid] = (bf16_t)v;
    } else {
        int tid = (b - EB_BLOCKS - CX_BLOCKS) * 256 + threadIdx.x;
        if (tid < S1) {
            int n = tid / K1, k = tid - n * K1;
            W1t[tid] = (bf16_t)((k < F_IN) ? W1[k * HID + n] : 0.f);
        } else if (tid < S1 + S2) {
            int t = tid - S1;
            int n = t >> 9, k = t & 511;
            W2t[t] = (bf16_t)W2[k * HID + n];
        } else if (tid < S1 + S2 + S3) {
            int t = tid - S1 - S2;
            int n = t >> 10, k = t & 1023;
            Bst[t] = (bf16_t)((k < HID) ? Wl[k * HID + n] : Wr[(k - HID) * HID + n]);
        } else if (tid < S1 + S2 + S3 + S4) {
            int t = tid - S1 - S2 - S3;
            int n = t / DENSE_F, k = t - n * DENSE_F;
            float v = (n < 4) ? g1W[k * 4 + n] : (n < NHEADS) ? g2W[k * 16 + (n - 4)] : 0.f;
            Wgt[t] = (bf16_t)v;
        } else if (tid < S1 + S2 + S3 + S4 + NHEADS) {
            int hh = tid - S1 - S2 - S3 - S4;
            asrc[hh] = (hh < 4) ? a1s[hh] : a2s[hh - 4];
            adst[hh] = (hh < 4) ? a1d[hh] : a2d[hh - 4];
        }
    }
}

// ---------------------------------------------------------------------------
// Fast exclusive scan of cnt -> rowptr/woff, + node_stats fold (deg+1, rsqrt).
// ---------------------------------------------------------------------------
#define SEG 30
__global__ __launch_bounds__(1024) void scan_rowptr_fast(
    const int* __restrict__ cnt, int* __restrict__ rowptr, int* __restrict__ woff,
    float* __restrict__ deg, float* __restrict__ dinv)
{
    int t = threadIdx.x;
    int base = t * SEG;
    int v[SEG];
    int sum = 0;
#pragma unroll
    for (int j = 0; j < SEG; ++j) {
        int i = base + j;
        int c = (i < N_NODES) ? cnt[i] : 0;
        v[j] = c;
        sum += c;
        if (i < N_NODES) {
            float d = deg[i] + 1.0f;   // self-loop weight 1
            deg[i] = d;
            dinv[i] = rsqrtf(d);
        }
    }
    int lane = t & 63;
    int wid = t >> 6;
    int s = sum;
#pragma unroll
    for (int off = 1; off < 64; off <<= 1) {
        int u = __shfl_up(s, off);
        if (lane >= off) s += u;
    }
    __shared__ int wsum[16];
    if (lane == 63) wsum[wid] = s;
    __syncthreads();
    if (t < 16) {
        int ws = wsum[t];
#pragma unroll
        for (int off = 1; off < 16; off <<= 1) {
            int u = __shfl_up(ws, off);
            if (t >= off) ws += u;
        }
        wsum[t] = ws;
    }
    __syncthreads();
    int carry = (wid > 0) ? wsum[wid - 1] : 0;
    int excl = carry + s - sum;   // exclusive prefix for this thread's segment
#pragma unroll
    for (int j = 0; j < SEG; ++j) {
        int i = base + j;
        if (i < N_NODES) { rowptr[i] = excl; woff[i] = excl; }
        excl += v[j];
    }
    if (t == 1023) rowptr[N_NODES] = excl;   // total edge count
}

__global__ __launch_bounds__(256) void scatter_csr(
    const int* __restrict__ src, const int* __restrict__ dst,
    const float* __restrict__ ew, int* __restrict__ woff,
    int* __restrict__ col, float* __restrict__ wcsr)
{
    int e = blockIdx.x * 256 + threadIdx.x;
    if (e >= N_EDGES) return;
    int t = dst[e];
    int p = atomicAdd(&woff[t], 1);
    col[p] = src[e];
    wcsr[p] = ew[e];
}

// ---------------------------------------------------------------------------
// Bijective XCD remap (m204): hardware block d -> logical l so each XCD gets
// a CONTIGUOUS run of logical ids. Then x = l % gx shares the A-row panel and
// the whole B matrix within one XCD's L2.
// ---------------------------------------------------------------------------
__device__ __forceinline__ void xcd_remap(int nwg, int gx, int& bx, int& by)
{
    int d = blockIdx.x;
    int xcd = d & 7, pos = d >> 3;
    int q = nwg >> 3, r = nwg & 7;
    int l = (xcd < r ? xcd * (q + 1) : r * (q + 1) + (xcd - r) * q) + pos;
    bx = l % gx;
    by = l / gx;
}

// ---------------------------------------------------------------------------
// bf16 MFMA GEMM (NT) body, 3-buffer 2-deep pipeline (T3+T4):
//   step s: stage((s+2)%3); s_waitcnt vmcnt(8); s_barrier;
//           ds_read buf[s%3] + MFMA; s_barrier.
// Tail: vmcnt(4) then vmcnt(0). (Verified passing in R5.)
// ---------------------------------------------------------------------------
#define BUF_E (128 * 32)
__device__ __forceinline__ void gemm_body(
    const bf16_t* __restrict__ A1, int lda1, int ksplit,
    const bf16_t* __restrict__ A2, int lda2,
    const bf16_t* __restrict__ Bt, int ldb,
    float* __restrict__ C, bf16_t* __restrict__ Cb, long ldc, int K,
    const float* __restrict__ bias, int ncols,
    int n0, long r0, bf16_t* smem)
{
    const int tid = threadIdx.x;
    const int wid = tid >> 6, lane = tid & 63;
    const int li = lane & 15, kq = lane >> 4;
    const int wm = (wid >> 1) * 64, wn = (wid & 1) * 64;

    f32x4 acc[4][4] = {};

    const int s0 = wid * 64 + lane;
    const int s1 = 256 + s0;
    const int am0 = s0 >> 2, ak0 = (s0 & 3) ^ ((am0 >> 1) & 3);
    const int am1 = s1 >> 2, ak1 = (s1 & 3) ^ ((am1 >> 1) & 3);
    const int swz = (li >> 1) & 3;

    auto stage = [&](int buf, int k0) {
        const bf16_t* Ab; int lda;
        if (k0 < ksplit) { Ab = A1 + k0;            lda = lda1; }
        else             { Ab = A2 + (k0 - ksplit); lda = lda2; }
        bf16_t* Asb = smem + buf * (2 * BUF_E);
        bf16_t* Bsb = Asb + BUF_E;
        __builtin_amdgcn_global_load_lds(
            (const __attribute__((address_space(1))) void*)(Ab + (r0 + am0) * (long)lda + ak0 * 8),
            (__attribute__((address_space(3))) void*)(Asb + (wid * 64) * 8), 16, 0, 0);
        __builtin_amdgcn_global_load_lds(
            (const __attribute__((address_space(1))) void*)(Ab + (r0 + am1) * (long)lda + ak1 * 8),
            (__attribute__((address_space(3))) void*)(Asb + (256 + wid * 64) * 8), 16, 0, 0);
        __builtin_amdgcn_global_load_lds(
            (const __attribute__((address_space(1))) void*)(Bt + (n0 + am0) * (long)ldb + k0 + ak0 * 8),
            (__attribute__((address_space(3))) void*)(Bsb + (wid * 64) * 8), 16, 0, 0);
        __builtin_amdgcn_global_load_lds(
            (const __attribute__((address_space(1))) void*)(Bt + (n0 + am1) * (long)ldb + k0 + ak1 * 8),
            (__attribute__((address_space(3))) void*)(Bsb + (256 + wid * 64) * 8), 16, 0, 0);
    };

    const int nsteps = K >> 5;     // all call sites have nsteps >= 12
    stage(0, 0);
    stage(1, 32);

    int cur = 0, nx2 = 2;
    for (int s = 0; s < nsteps; ++s) {
        if (s + 2 < nsteps) {
            stage(nx2, (s + 2) << 5);
            asm volatile("s_waitcnt vmcnt(8)" ::: "memory");
        } else if (s + 2 == nsteps) {
            asm volatile("s_waitcnt vmcnt(4)" ::: "memory");
        } else {
            asm volatile("s_waitcnt vmcnt(0)" ::: "memory");
        }
        __builtin_amdgcn_s_barrier();          // buf[cur] fully staged (all waves)
        __builtin_amdgcn_sched_barrier(0);

        const bf16_t* Asb = smem + cur * (2 * BUF_E);
        const bf16_t* Bsb = Asb + BUF_E;
        bf16x8 a[4], b[4];
#pragma unroll
        for (int f = 0; f < 4; ++f) {
            int m = wm + f * 16 + li;
            a[f] = *(const bf16x8*)(Asb + m * 32 + ((kq ^ swz) * 8));
            int n = wn + f * 16 + li;
            b[f] = *(const bf16x8*)(Bsb + n * 32 + ((kq ^ swz) * 8));
        }
#pragma unroll
        for (int fm = 0; fm < 4; ++fm)
#pragma unroll
            for (int fn = 0; fn < 4; ++fn)
                acc[fm][fn] = __builtin_amdgcn_mfma_f32_16x16x32_bf16(
                    a[fm], b[fn], acc[fm][fn], 0, 0, 0);

        __builtin_amdgcn_sched_barrier(0);
        __builtin_amdgcn_s_barrier();          // reads done before buf reuse
        __builtin_amdgcn_sched_barrier(0);

        cur = (cur == 2) ? 0 : cur + 1;
        nx2 = (nx2 == 2) ? 0 : nx2 + 1;
    }

    // C/D layout: col = lane&15, row = (lane>>4)*4 + reg
#pragma unroll
    for (int fm = 0; fm < 4; ++fm) {
#pragma unroll
        for (int r = 0; r < 4; ++r) {
            long row = r0 + wm + fm * 16 + kq * 4 + r;
            if (row >= N_NODES) continue;
#pragma unroll
            for (int fn = 0; fn < 4; ++fn) {
                int colg = n0 + wn + fn * 16 + li;
                if (colg >= ncols) continue;
                float v = acc[fm][fn][r];
                if (bias) v = fmaxf(v + bias[colg], 0.f);
                if (C)  C[row * ldc + colg]  = v;
                if (Cb) Cb[row * ldc + colg] = (bf16_t)v;
            }
        }
    }
}

// 1D grid; gx = tiles along N. XCD-swizzled decode.
__global__ __launch_bounds__(256) void gemm_bf16(
    const bf16_t* __restrict__ A1, int lda1, int ksplit,
    const bf16_t* __restrict__ A2, int lda2,
    const bf16_t* __restrict__ Bt, int ldb,
    float* __restrict__ C, bf16_t* __restrict__ Cb, long ldc, int K,
    const float* __restrict__ bias, int ncols, int gx)
{
    __shared__ bf16_t smem[3 * 2 * BUF_E];
    int bx, by;
    xcd_remap((int)gridDim.x, gx, bx, by);
    gemm_body(A1, lda1, ksplit, A2, lda2, Bt, ldb, C, Cb, ldc, K, bias, ncols,
              bx * 128, (long)by * 128, smem);
}

// Two independent GEMMs (GCN2 + SAGE) in one launch: bx<4 -> set 0.
__global__ __launch_bounds__(256) void gemm_bf16_dual(
    const bf16_t* __restrict__ A1a, int lda1a, int ksplita,
    const bf16_t* __restrict__ A2a, int lda2a,
    const bf16_t* __restrict__ Bta, int ldba,
    float* __restrict__ Ca, bf16_t* __restrict__ Cba, long ldca, int Ka,
    const float* __restrict__ biasa, int ncolsa,
    const bf16_t* __restrict__ A1b, int lda1b, int ksplitb,
    const bf16_t* __restrict__ A2b, int lda2b,
    const bf16_t* __restrict__ Btb, int ldbb,
    float* __restrict__ Cb2, bf16_t* __restrict__ Cbb, long ldcb, int Kb,
    const float* __restrict__ biasb, int ncolsb)
{
    __shared__ bf16_t smem[3 * 2 * BUF_E];
    int bx, by;
    xcd_remap((int)gridDim.x, 8, bx, by);
    long r0 = (long)by * 128;
    if (bx < 4) {
        gemm_body(A1a, lda1a, ksplita, A2a, lda2a, Bta, ldba, Ca, Cba, ldca, Ka,
                  biasa, ncolsa, bx * 128, r0, smem);
    } else {
        gemm_body(A1b, lda1b, ksplitb, A2b, lda2b, Btb, ldbb, Cb2, Cbb, ldcb, Kb,
                  biasb, ncolsb, (bx - 4) * 128, r0, smem);
    }
}

// ---------------------------------------------------------------------------
// GCN aggregation over raw x_bf (384 cols): aggx[i] = x[i]/deg + sum norm*x[s]
// 4 nodes per 256-thread block (one wave each); 8-edge unroll (deep MLP).
// ---------------------------------------------------------------------------
__global__ __launch_bounds__(256) void agg_x(
    const bf16_t* __restrict__ xb, const int* __restrict__ rowptr,
    const int* __restrict__ col, const float* __restrict__ wcsr,
    const float* __restrict__ dinv, const float* __restrict__ deg,
    bf16_t* __restrict__ aggx)
{
    int i = blockIdx.x * 4 + (threadIdx.x >> 6);
    int lane = threadIdx.x & 63;
    int c = lane * 8;
    bool act = (c < K1);
    float di = dinv[i];
    float selfw = 1.0f / deg[i];
    float acc0[8] = {}, acc1[8] = {};
    if (act) {
        bf16x8 sv = *(const bf16x8*)(xb + (long)i * K1 + c);
#pragma unroll
        for (int j = 0; j < 8; ++j) acc0[j] = selfw * (float)sv[j];
    }
    int e = rowptr[i], e1 = rowptr[i + 1];
    for (; e + 7 < e1; e += 8) {
        int ss[8]; float ww[8];
#pragma unroll
        for (int q = 0; q < 8; ++q) ss[q] = col[e + q];
#pragma unroll
        for (int q = 0; q < 8; ++q) ww[q] = dinv[ss[q]] * wcsr[e + q] * di;
        if (act) {
            bf16x8 vv[8];
#pragma unroll
            for (int q = 0; q < 8; ++q)
                vv[q] = *(const bf16x8*)(xb + (long)ss[q] * K1 + c);
#pragma unroll
            for (int q = 0; q < 8; ++q) {
#pragma unroll
                for (int j = 0; j < 8; ++j) {
                    if (q & 1) acc1[j] = fmaf(ww[q], (float)vv[q][j], acc1[j]);
                    else       acc0[j] = fmaf(ww[q], (float)vv[q][j], acc0[j]);
                }
            }
        }
    }
    for (; e < e1; ++e) {
        int sA = col[e];
        float wA = dinv[sA] * wcsr[e] * di;
        if (act) {
            bf16x8 vA = *(const bf16x8*)(xb + (long)sA * K1 + c);
#pragma unroll
            for (int j = 0; j < 8; ++j) acc0[j] = fmaf(wA, (float)vA[j], acc0[j]);
        }
    }
    if (act) {
        bf16x8 ob;
#pragma unroll
        for (int j = 0; j < 8; ++j) ob[j] = (bf16_t)(acc0[j] + acc1[j]);
        *reinterpret_cast<bf16x8*>(aggx + (long)i * K1 + c) = ob;
    }
}

// ---------------------------------------------------------------------------
// Fused x1 aggregation: ONE gather of x1 rows serves GCN2 (norm-weighted sum
// + self) AND SAGE (plain mean). 4 nodes/block, 8-edge unroll.
// ---------------------------------------------------------------------------
__global__ __launch_bounds__(256) void agg_x1(
    const bf16_t* __restrict__ x1b /* dense_bf, cols [0,512) */,
    const int* __restrict__ rowptr, const int* __restrict__ col,
    const float* __restrict__ wcsr, const float* __restrict__ dinv,
    const float* __restrict__ deg, const int* __restrict__ cnt,
    bf16_t* __restrict__ gbf, bf16_t* __restrict__ meanb)
{
    int i = blockIdx.x * 4 + (threadIdx.x >> 6);
    int lane = threadIdx.x & 63;
    int c = lane * 8;
    float di = dinv[i];
    float selfw = 1.0f / deg[i];
    bf16x8 sv = *(const bf16x8*)(x1b + (long)i * DENSE_F + c);
    float g0[8], g1[8], m0[8], m1[8];
#pragma unroll
    for (int j = 0; j < 8; ++j) {
        g0[j] = selfw * (float)sv[j];
        g1[j] = 0.f; m0[j] = 0.f; m1[j] = 0.f;
    }
    int e = rowptr[i], e1 = rowptr[i + 1];
    for (; e + 7 < e1; e += 8) {
        int ss[8]; float ww[8];
#pragma unroll
        for (int q = 0; q < 8; ++q) ss[q] = col[e + q];
#pragma unroll
        for (int q = 0; q < 8; ++q) ww[q] = dinv[ss[q]] * wcsr[e + q] * di;
        bf16x8 vv[8];
#pragma unroll
        for (int q = 0; q < 8; ++q)
            vv[q] = *(const bf16x8*)(x1b + (long)ss[q] * DENSE_F + c);
#pragma unroll
        for (int q = 0; q < 8; ++q) {
#pragma unroll
            for (int j = 0; j < 8; ++j) {
                float f = (float)vv[q][j];
                if (q & 1) { g1[j] = fmaf(ww[q], f, g1[j]); m1[j] += f; }
                else       { g0[j] = fmaf(ww[q], f, g0[j]); m0[j] += f; }
            }
        }
    }
    for (; e < e1; ++e) {
        int sA = col[e];
        float wA = dinv[sA] * wcsr[e] * di;
        bf16x8 vA = *(const bf16x8*)(x1b + (long)sA * DENSE_F + c);
#pragma unroll
        for (int j = 0; j < 8; ++j) {
            float fA = (float)vA[j];
            g0[j] = fmaf(wA, fA, g0[j]);
            m0[j] += fA;
        }
    }
    float inv = 1.0f / fmaxf((float)cnt[i], 1.0f);
    bf16x8 og, om;
#pragma unroll
    for (int j = 0; j < 8; ++j) {
        og[j] = (bf16_t)(g0[j] + g1[j]);
        om[j] = (bf16_t)((m0[j] + m1[j]) * inv);
    }
    *reinterpret_cast<bf16x8*>(gbf   + (long)i * HID + c) = og;
    *reinterpret_cast<bf16x8*>(meanb + (long)i * HID + c) = om;
}

// ---------------------------------------------------------------------------
// per-dst GAT attention over CSR (+self loop), softmax shift-free.
// REPACKED: 32 lanes per node (heads 0..19 active), 2 nodes/wave, 8/block.
// 8-edge unroll. Halves wave count vs 64-lane layout; lane util 31%->62%.
// ---------------------------------------------------------------------------
__global__ __launch_bounds__(256) void gat_agg(
    const float* __restrict__ hgat, const int* __restrict__ rowptr,
    const int* __restrict__ col, const float* __restrict__ asrc,
    const float* __restrict__ adst, const float* __restrict__ b1p,
    const float* __restrict__ b2p, float* __restrict__ xout)
{
    int i = blockIdx.x * 8 + (threadIdx.x >> 5);
    int l32 = threadIdx.x & 31;
    int h = (l32 < NHEADS) ? l32 : 0;
    float hg_i = hgat[(long)i * HG_LD + h];
    float as = asrc[h], ad = adst[h];
    float adhg = ad * hg_i;
    float ev = hg_i * as + adhg;
    ev = ev > 0.f ? ev : 0.2f * ev;
    float ex = __expf(ev);
    float den0 = ex, og0 = ex * hg_i, den1 = 0.f, og1 = 0.f;
    int e = rowptr[i], e1 = rowptr[i + 1];
    for (; e + 7 < e1; e += 8) {
        int ss[8];
#pragma unroll
        for (int q = 0; q < 8; ++q) ss[q] = col[e + q];
        float hh[8];
#pragma unroll
        for (int q = 0; q < 8; ++q) hh[q] = hgat[(long)ss[q] * HG_LD + h];
#pragma unroll
        for (int q = 0; q < 8; ++q) {
            float t = fmaf(hh[q], as, adhg); t = t > 0.f ? t : 0.2f * t;
            float xq = __expf(t);
            if (q & 1) { den1 += xq; og1 = fmaf(xq, hh[q], og1); }
            else       { den0 += xq; og0 = fmaf(xq, hh[q], og0); }
        }
    }
    for (; e < e1; ++e) {
        int sA = col[e];
        float hA = hgat[(long)sA * HG_LD + h];
        float tA = fmaf(hA, as, adhg); tA = tA > 0.f ? tA : 0.2f * tA;
        float xA = __expf(tA);
        den0 += xA; og0 = fmaf(xA, hA, og0);
    }
    float out = (l32 < NHEADS) ? (og0 + og1) / (den0 + den1) : 0.f;
    // reduce 4-head groups within the 32-lane node group
    float s4 = out + __shfl_xor(out, 1);
    s4 += __shfl_xor(s4, 2);
    int base = (threadIdx.x & 63) & 32;   // wave-lane base of this node's group
    float g0 = __shfl(s4, base + 0);
    float g1 = __shfl(s4, base + 4);
    float g2 = __shfl(s4, base + 8);
    float g3 = __shfl(s4, base + 12);
    float g4 = __shfl(s4, base + 16);
    if (l32 == 0) {
        float a1 = g0 * 0.25f + b1p[0];
        float a2 = (g1 + g2 + g3 + g4) * 0.0625f + b2p[0];
        xout[i] = 0.5f * (a1 + a2);
    }
}

// ---------------------------------------------------------------------------
extern "C" void kernel_launch(void* const* d_in, const int* in_sizes, int n_in,
                              void* d_out, int out_size, void* d_ws, size_t ws_size,
                              hipStream_t stream) {
    (void)in_sizes; (void)n_in; (void)out_size; (void)ws_size;
    const float* x    = (const float*)d_in[0];
    const int*   ei   = (const int*)d_in[1];
    const float* ew   = (const float*)d_in[2];
    const float* W1   = (const float*)d_in[3];
    const float* b1   = (const float*)d_in[4];
    const float* W2   = (const float*)d_in[5];
    const float* b2   = (const float*)d_in[6];
    const float* sWl  = (const float*)d_in[7];
    const float* sWr  = (const float*)d_in[8];
    const float* sb   = (const float*)d_in[9];
    const float* g1W  = (const float*)d_in[10];
    const float* g1as = (const float*)d_in[11];
    const float* g1ad = (const float*)d_in[12];
    const float* g1b  = (const float*)d_in[13];
    const float* g2W  = (const float*)d_in[14];
    const float* g2as = (const float*)d_in[15];
    const float* g2ad = (const float*)d_in[16];
    const float* g2b  = (const float*)d_in[17];

    const int* src = ei;
    const int* dst = ei + N_EDGES;

    float* xout  = (float*)d_out;          // [N]
    float* dense = xout + N_NODES;         // [N,1536] fp32 (output 2)

    size_t off = 0;
    auto alloc = [&](size_t nbytes) -> void* {
        void* p = (char*)d_ws + off;
        off += (nbytes + 255) & ~(size_t)255;
        return p;
    };
    bf16_t* dense_bf = (bf16_t*)alloc((size_t)M_PAD * DENSE_F * 2);
    bf16_t* x_bf     = (bf16_t*)alloc((size_t)M_PAD * K1 * 2);
    bf16_t* aggx_bf  = (bf16_t*)alloc((size_t)M_PAD * K1 * 2);
    bf16_t* g_bf     = (bf16_t*)alloc((size_t)M_PAD * HID * 2);
    bf16_t* mean_bf  = (bf16_t*)alloc((size_t)M_PAD * HID * 2);
    float*  hgat     = (float*)alloc((size_t)M_PAD * HG_LD * 4);
    bf16_t* W1t      = (bf16_t*)alloc((size_t)512 * K1 * 2);
    bf16_t* W2t      = (bf16_t*)alloc((size_t)512 * 512 * 2);
    bf16_t* Bst      = (bf16_t*)alloc((size_t)512 * 1024 * 2);
    bf16_t* Wgt      = (bf16_t*)alloc((size_t)128 * DENSE_F * 2);
    float*  deg      = (float*)alloc((size_t)N_NODES * 4);
    float*  dinv     = (float*)alloc((size_t)N_NODES * 4);
    float*  asrc     = (float*)alloc(32 * 4);
    float*  adst     = (float*)alloc(32 * 4);
    int*    cnt      = (int*)alloc((size_t)N_NODES * 4);
    int*    rowp     = (int*)alloc((size_t)(N_NODES + 1) * 4);
    int*    woff     = (int*)alloc((size_t)N_NODES * 4);
    int*    colx     = (int*)alloc((size_t)N_EDGES * 4);
    float*  wcsr     = (float*)alloc((size_t)N_EDGES * 4);

    const int EB = EB_BLOCKS;

    hipMemsetAsync(deg, 0, (size_t)N_NODES * 4, stream);
    hipMemsetAsync(cnt, 0, (size_t)N_NODES * 4, stream);

    // Fused: build_stats || conv_x || pack_weights
    prologue<<<PRO_BLOCKS, 256, 0, stream>>>(
        dst, ew, deg, cnt, x, x_bf,
        W1, W2, sWl, sWr, g1W, g2W, g1as, g1ad, g2as, g2ad,
        W1t, W2t, Bst, Wgt, asrc, adst);
    // Fused: exclusive scan + node_stats (deg+1, rsqrt)
    scan_rowptr_fast<<<1, 1024, 0, stream>>>(cnt, rowp, woff, deg, dinv);
    scatter_csr<<<EB, 256, 0, stream>>>(src, dst, ew, woff, colx, wcsr);

    const dim3 gB(256);
    const int NT = M_PAD / 128;                   // 235 row tiles

    // GCN1 (commuted): aggx = A_gcn * x ; x1 = relu(aggx@W1 + b1) -> dense[:,0:512]
    agg_x<<<N_NODES / 4, 256, 0, stream>>>(x_bf, rowp, colx, wcsr, dinv, deg, aggx_bf);
    gemm_bf16<<<4 * NT, gB, 0, stream>>>(aggx_bf, K1, K1, aggx_bf, K1, W1t, K1,
                                         dense, dense_bf, DENSE_F, K1, b1, 512, 4);

    // Fused x1 gather: g = A_gcn * x1 (GCN2), mean = mean(x1) (SAGE)
    agg_x1<<<N_NODES / 4, 256, 0, stream>>>(dense_bf, rowp, colx, wcsr, dinv, deg, cnt,
                                            g_bf, mean_bf);
    // GCN2 + SAGE fused into one launch (independent GEMMs):
    //   x2 = relu(g@W2 + b2)                 -> dense[:,512:1024]
    //   x3 = relu([mean|x1]@[Wl;Wr] + sb)    -> dense[:,1024:1536]
    gemm_bf16_dual<<<8 * NT, gB, 0, stream>>>(
        g_bf, HID, HID, g_bf, HID, W2t, HID,
        dense + HID, dense_bf + HID, DENSE_F, HID, b2, 512,
        mean_bf, HID, HID, dense_bf, DENSE_F, Bst, 1024,
        dense + 2 * HID, dense_bf + 2 * HID, DENSE_F, 1024, sb, 512);

    // GAT: hgat = dense @ Wg (fp32, masked to 32 cols, stride 32), then aggregate
    gemm_bf16<<<1 * NT, gB, 0, stream>>>(dense_bf, DENSE_F, DENSE_F, dense_bf, DENSE_F,
                                         Wgt, DENSE_F, hgat, nullptr, HG_LD,
                                         DENSE_F, nullptr, HG_LD, 1);
    gat_agg<<<N_NODES / 8, 256, 0, stream>>>(hgat, rowp, colx, asrc, adst, g1b, g2b, xout);
}

// Round 7
// 741.204 us; speedup vs baseline: 1.1302x; 1.0274x over previous
//
#include <hip/hip_runtime.h>
#include <hip/hip_bf16.h>
#include <stdint.h>

#define N_NODES 30000
#define M_PAD   30080      // 235 * 128, GEMM M padding
#define N_EDGES 480000
#define F_IN 376
#define K1   384           // F_IN padded to BK multiple
#define HID 512
#define DENSE_F 1536
#define NHEADS 20          // 4 (gat1) + 16 (gat2)
#define HG_LD 32           // hgat leading dim (fp32): 3.85 MB, L2-resident

typedef __bf16 bf16_t;
typedef bf16_t bf16x4 __attribute__((ext_vector_type(4)));
typedef bf16_t bf16x8 __attribute__((ext_vector_type(8)));
typedef float  f32x4  __attribute__((ext_vector_type(4)));

#define S1 (512 * K1)
#define S2 (512 * 512)
#define S3 (512 * 1024)
#define S4 (128 * DENSE_F)
#define PW_ELEMS (S1 + S2 + S3 + S4 + NHEADS)

#define EB_BLOCKS ((N_EDGES + 255) / 256)
#define CX_BLOCKS ((M_PAD * K1) / (256 * 4))     // 11280: 4 elems/thread
#define PW_BLOCKS ((PW_ELEMS + 255) / 256)
#define PRO_BLOCKS (EB_BLOCKS + CX_BLOCKS + PW_BLOCKS)

// ---------------------------------------------------------------------------
// Fused prologue: three independent stages run concurrently in one launch.
//   conv_x section vectorized: float4 load -> bf16x4 store (G13).
// ---------------------------------------------------------------------------
__global__ __launch_bounds__(256) void prologue(
    const int* __restrict__ dst, const float* __restrict__ ew,
    float* __restrict__ deg, int* __restrict__ cnt,
    const float* __restrict__ x, bf16_t* __restrict__ xb,
    const float* __restrict__ W1, const float* __restrict__ W2,
    const float* __restrict__ Wl, const float* __restrict__ Wr,
    const float* __restrict__ g1W, const float* __restrict__ g2W,
    const float* __restrict__ a1s, const float* __restrict__ a1d,
    const float* __restrict__ a2s, const float* __restrict__ a2d,
    bf16_t* __restrict__ W1t, bf16_t* __restrict__ W2t,
    bf16_t* __restrict__ Bst, bf16_t* __restrict__ Wgt,
    float* __restrict__ asrc, float* __restrict__ adst)
{
    int b = blockIdx.x;
    if (b < EB_BLOCKS) {
        int e = b * 256 + threadIdx.x;
        if (e >= N_EDGES) return;
        int t = dst[e];
        atomicAdd(&deg[t], ew[e]);
        atomicAdd(&cnt[t], 1);
    } else if (b < EB_BLOCKS + CX_BLOCKS) {
        int t4 = (b - EB_BLOCKS) * 256 + threadIdx.x;
        int base = t4 * 4;                       // flat idx into [M_PAD x K1]
        int r = base / K1, c = base - r * K1;    // c multiple of 4; no row cross
        bf16x4 ob = {};
        if (r < N_NODES && c < F_IN) {           // c<=372 -> c+3 <= 375 in range
            float4 v = *(const float4*)(x + (long)r * F_IN + c);
            ob[0] = (bf16_t)v.x; ob[1] = (bf16_t)v.y;
            ob[2] = (bf16_t)v.z; ob[3] = (bf16_t)v.w;
        }
        *reinterpret_cast<bf16x4*>(xb + base) = ob;
    } else {
        int tid = (b - EB_BLOCKS - CX_BLOCKS) * 256 + threadIdx.x;
        if (tid < S1) {
            int n = tid / K1, k = tid - n * K1;
            W1t[tid] = (bf16_t)((k < F_IN) ? W1[k * HID + n] : 0.f);
        } else if (tid < S1 + S2) {
            int t = tid - S1;
            int n = t >> 9, k = t & 511;
            W2t[t] = (bf16_t)W2[k * HID + n];
        } else if (tid < S1 + S2 + S3) {
            int t = tid - S1 - S2;
            int n = t >> 10, k = t & 1023;
            Bst[t] = (bf16_t)((k < HID) ? Wl[k * HID + n] : Wr[(k - HID) * HID + n]);
        } else if (tid < S1 + S2 + S3 + S4) {
            int t = tid - S1 - S2 - S3;
            int n = t / DENSE_F, k = t - n * DENSE_F;
            float v = (n < 4) ? g1W[k * 4 + n] : (n < NHEADS) ? g2W[k * 16 + (n - 4)] : 0.f;
            Wgt[t] = (bf16_t)v;
        } else if (tid < S1 + S2 + S3 + S4 + NHEADS) {
            int hh = tid - S1 - S2 - S3 - S4;
            asrc[hh] = (hh < 4) ? a1s[hh] : a2s[hh - 4];
            adst[hh] = (hh < 4) ? a1d[hh] : a2d[hh - 4];
        }
    }
}

// ---------------------------------------------------------------------------
// Fast exclusive scan of cnt -> rowptr/woff, + node_stats fold (deg+1, rsqrt).
// ---------------------------------------------------------------------------
#define SEG 30
__global__ __launch_bounds__(1024) void scan_rowptr_fast(
    const int* __restrict__ cnt, int* __restrict__ rowptr, int* __restrict__ woff,
    float* __restrict__ deg, float* __restrict__ dinv)
{
    int t = threadIdx.x;
    int base = t * SEG;
    int v[SEG];
    int sum = 0;
#pragma unroll
    for (int j = 0; j < SEG; ++j) {
        int i = base + j;
        int c = (i < N_NODES) ? cnt[i] : 0;
        v[j] = c;
        sum += c;
        if (i < N_NODES) {
            float d = deg[i] + 1.0f;   // self-loop weight 1
            deg[i] = d;
            dinv[i] = rsqrtf(d);
        }
    }
    int lane = t & 63;
    int wid = t >> 6;
    int s = sum;
#pragma unroll
    for (int off = 1; off < 64; off <<= 1) {
        int u = __shfl_up(s, off);
        if (lane >= off) s += u;
    }
    __shared__ int wsum[16];
    if (lane == 63) wsum[wid] = s;
    __syncthreads();
    if (t < 16) {
        int ws = wsum[t];
#pragma unroll
        for (int off = 1; off < 16; off <<= 1) {
            int u = __shfl_up(ws, off);
            if (t >= off) ws += u;
        }
        wsum[t] = ws;
    }
    __syncthreads();
    int carry = (wid > 0) ? wsum[wid - 1] : 0;
    int excl = carry + s - sum;   // exclusive prefix for this thread's segment
#pragma unroll
    for (int j = 0; j < SEG; ++j) {
        int i = base + j;
        if (i < N_NODES) { rowptr[i] = excl; woff[i] = excl; }
        excl += v[j];
    }
    if (t == 1023) rowptr[N_NODES] = excl;   // total edge count
}

// scatter + normalized-weight precompute: wcsr[p] = ew[e] * dinv[src[e]].
// agg kernels then use w = wcsr*di -- bit-exact vs (dinv[s]*ew)*di.
__global__ __launch_bounds__(256) void scatter_csr(
    const int* __restrict__ src, const int* __restrict__ dst,
    const float* __restrict__ ew, const float* __restrict__ dinv,
    int* __restrict__ woff, int* __restrict__ col, float* __restrict__ wcsr)
{
    int e = blockIdx.x * 256 + threadIdx.x;
    if (e >= N_EDGES) return;
    int t = dst[e];
    int s = src[e];
    int p = atomicAdd(&woff[t], 1);
    col[p] = s;
    wcsr[p] = ew[e] * dinv[s];
}

// ---------------------------------------------------------------------------
// Bijective XCD remap (m204).
// ---------------------------------------------------------------------------
__device__ __forceinline__ void xcd_remap(int nwg, int gx, int& bx, int& by)
{
    int d = blockIdx.x;
    int xcd = d & 7, pos = d >> 3;
    int q = nwg >> 3, r = nwg & 7;
    int l = (xcd < r ? xcd * (q + 1) : r * (q + 1) + (xcd - r) * q) + pos;
    bx = l % gx;
    by = l / gx;
}

// ---------------------------------------------------------------------------
// bf16 MFMA GEMM (NT) body, 3-buffer 2-deep pipeline (T3+T4). R5-verified.
// ---------------------------------------------------------------------------
#define BUF_E (128 * 32)
__device__ __forceinline__ void gemm_body(
    const bf16_t* __restrict__ A1, int lda1, int ksplit,
    const bf16_t* __restrict__ A2, int lda2,
    const bf16_t* __restrict__ Bt, int ldb,
    float* __restrict__ C, bf16_t* __restrict__ Cb, long ldc, int K,
    const float* __restrict__ bias, int ncols,
    int n0, long r0, bf16_t* smem)
{
    const int tid = threadIdx.x;
    const int wid = tid >> 6, lane = tid & 63;
    const int li = lane & 15, kq = lane >> 4;
    const int wm = (wid >> 1) * 64, wn = (wid & 1) * 64;

    f32x4 acc[4][4] = {};

    const int s0 = wid * 64 + lane;
    const int s1 = 256 + s0;
    const int am0 = s0 >> 2, ak0 = (s0 & 3) ^ ((am0 >> 1) & 3);
    const int am1 = s1 >> 2, ak1 = (s1 & 3) ^ ((am1 >> 1) & 3);
    const int swz = (li >> 1) & 3;

    auto stage = [&](int buf, int k0) {
        const bf16_t* Ab; int lda;
        if (k0 < ksplit) { Ab = A1 + k0;            lda = lda1; }
        else             { Ab = A2 + (k0 - ksplit); lda = lda2; }
        bf16_t* Asb = smem + buf * (2 * BUF_E);
        bf16_t* Bsb = Asb + BUF_E;
        __builtin_amdgcn_global_load_lds(
            (const __attribute__((address_space(1))) void*)(Ab + (r0 + am0) * (long)lda + ak0 * 8),
            (__attribute__((address_space(3))) void*)(Asb + (wid * 64) * 8), 16, 0, 0);
        __builtin_amdgcn_global_load_lds(
            (const __attribute__((address_space(1))) void*)(Ab + (r0 + am1) * (long)lda + ak1 * 8),
            (__attribute__((address_space(3))) void*)(Asb + (256 + wid * 64) * 8), 16, 0, 0);
        __builtin_amdgcn_global_load_lds(
            (const __attribute__((address_space(1))) void*)(Bt + (n0 + am0) * (long)ldb + k0 + ak0 * 8),
            (__attribute__((address_space(3))) void*)(Bsb + (wid * 64) * 8), 16, 0, 0);
        __builtin_amdgcn_global_load_lds(
            (const __attribute__((address_space(1))) void*)(Bt + (n0 + am1) * (long)ldb + k0 + ak1 * 8),
            (__attribute__((address_space(3))) void*)(Bsb + (256 + wid * 64) * 8), 16, 0, 0);
    };

    const int nsteps = K >> 5;     // all call sites have nsteps >= 12
    stage(0, 0);
    stage(1, 32);

    int cur = 0, nx2 = 2;
    for (int s = 0; s < nsteps; ++s) {
        if (s + 2 < nsteps) {
            stage(nx2, (s + 2) << 5);
            asm volatile("s_waitcnt vmcnt(8)" ::: "memory");
        } else if (s + 2 == nsteps) {
            asm volatile("s_waitcnt vmcnt(4)" ::: "memory");
        } else {
            asm volatile("s_waitcnt vmcnt(0)" ::: "memory");
        }
        __builtin_amdgcn_s_barrier();          // buf[cur] fully staged (all waves)
        __builtin_amdgcn_sched_barrier(0);

        const bf16_t* Asb = smem + cur * (2 * BUF_E);
        const bf16_t* Bsb = Asb + BUF_E;
        bf16x8 a[4], b[4];
#pragma unroll
        for (int f = 0; f < 4; ++f) {
            int m = wm + f * 16 + li;
            a[f] = *(const bf16x8*)(Asb + m * 32 + ((kq ^ swz) * 8));
            int n = wn + f * 16 + li;
            b[f] = *(const bf16x8*)(Bsb + n * 32 + ((kq ^ swz) * 8));
        }
#pragma unroll
        for (int fm = 0; fm < 4; ++fm)
#pragma unroll
            for (int fn = 0; fn < 4; ++fn)
                acc[fm][fn] = __builtin_amdgcn_mfma_f32_16x16x32_bf16(
                    a[fm], b[fn], acc[fm][fn], 0, 0, 0);

        __builtin_amdgcn_sched_barrier(0);
        __builtin_amdgcn_s_barrier();          // reads done before buf reuse
        __builtin_amdgcn_sched_barrier(0);

        cur = (cur == 2) ? 0 : cur + 1;
        nx2 = (nx2 == 2) ? 0 : nx2 + 1;
    }

    // C/D layout: col = lane&15, row = (lane>>4)*4 + reg
#pragma unroll
    for (int fm = 0; fm < 4; ++fm) {
#pragma unroll
        for (int r = 0; r < 4; ++r) {
            long row = r0 + wm + fm * 16 + kq * 4 + r;
            if (row >= N_NODES) continue;
#pragma unroll
            for (int fn = 0; fn < 4; ++fn) {
                int colg = n0 + wn + fn * 16 + li;
                if (colg >= ncols) continue;
                float v = acc[fm][fn][r];
                if (bias) v = fmaxf(v + bias[colg], 0.f);
                if (C)  C[row * ldc + colg]  = v;
                if (Cb) Cb[row * ldc + colg] = (bf16_t)v;
            }
        }
    }
}

// 1D grid; gx = tiles along N. XCD-swizzled decode.
__global__ __launch_bounds__(256) void gemm_bf16(
    const bf16_t* __restrict__ A1, int lda1, int ksplit,
    const bf16_t* __restrict__ A2, int lda2,
    const bf16_t* __restrict__ Bt, int ldb,
    float* __restrict__ C, bf16_t* __restrict__ Cb, long ldc, int K,
    const float* __restrict__ bias, int ncols, int gx)
{
    __shared__ bf16_t smem[3 * 2 * BUF_E];
    int bx, by;
    xcd_remap((int)gridDim.x, gx, bx, by);
    gemm_body(A1, lda1, ksplit, A2, lda2, Bt, ldb, C, Cb, ldc, K, bias, ncols,
              bx * 128, (long)by * 128, smem);
}

// Two independent GEMMs (GCN2 + SAGE) in one launch: bx<4 -> set 0.
__global__ __launch_bounds__(256) void gemm_bf16_dual(
    const bf16_t* __restrict__ A1a, int lda1a, int ksplita,
    const bf16_t* __restrict__ A2a, int lda2a,
    const bf16_t* __restrict__ Bta, int ldba,
    float* __restrict__ Ca, bf16_t* __restrict__ Cba, long ldca, int Ka,
    const float* __restrict__ biasa, int ncolsa,
    const bf16_t* __restrict__ A1b, int lda1b, int ksplitb,
    const bf16_t* __restrict__ A2b, int lda2b,
    const bf16_t* __restrict__ Btb, int ldbb,
    float* __restrict__ Cb2, bf16_t* __restrict__ Cbb, long ldcb, int Kb,
    const float* __restrict__ biasb, int ncolsb)
{
    __shared__ bf16_t smem[3 * 2 * BUF_E];
    int bx, by;
    xcd_remap((int)gridDim.x, 8, bx, by);
    long r0 = (long)by * 128;
    if (bx < 4) {
        gemm_body(A1a, lda1a, ksplita, A2a, lda2a, Bta, ldba, Ca, Cba, ldca, Ka,
                  biasa, ncolsa, bx * 128, r0, smem);
    } else {
        gemm_body(A1b, lda1b, ksplitb, A2b, lda2b, Btb, ldbb, Cb2, Cbb, ldcb, Kb,
                  biasb, ncolsb, (bx - 4) * 128, r0, smem);
    }
}

// ---------------------------------------------------------------------------
// GCN aggregation over raw x_bf (384 cols): aggx[i] = x[i]/deg + sum w*x[s].
// wcsr is pre-normalized (dinv[src] folded in) -> no per-edge dinv gather.
// ---------------------------------------------------------------------------
__global__ __launch_bounds__(256) void agg_x(
    const bf16_t* __restrict__ xb, const int* __restrict__ rowptr,
    const int* __restrict__ col, const float* __restrict__ wcsr,
    const float* __restrict__ dinv, const float* __restrict__ deg,
    bf16_t* __restrict__ aggx)
{
    int i = blockIdx.x * 4 + (threadIdx.x >> 6);
    int lane = threadIdx.x & 63;
    int c = lane * 8;
    bool act = (c < K1);
    float di = dinv[i];
    float selfw = 1.0f / deg[i];
    float acc0[8] = {}, acc1[8] = {};
    if (act) {
        bf16x8 sv = *(const bf16x8*)(xb + (long)i * K1 + c);
#pragma unroll
        for (int j = 0; j < 8; ++j) acc0[j] = selfw * (float)sv[j];
    }
    int e = rowptr[i], e1 = rowptr[i + 1];
    for (; e + 7 < e1; e += 8) {
        int ss[8]; float ww[8];
#pragma unroll
        for (int q = 0; q < 8; ++q) ss[q] = col[e + q];
#pragma unroll
        for (int q = 0; q < 8; ++q) ww[q] = wcsr[e + q] * di;
        if (act) {
            bf16x8 vv[8];
#pragma unroll
            for (int q = 0; q < 8; ++q)
                vv[q] = *(const bf16x8*)(xb + (long)ss[q] * K1 + c);
#pragma unroll
            for (int q = 0; q < 8; ++q) {
#pragma unroll
                for (int j = 0; j < 8; ++j) {
                    if (q & 1) acc1[j] = fmaf(ww[q], (float)vv[q][j], acc1[j]);
                    else       acc0[j] = fmaf(ww[q], (float)vv[q][j], acc0[j]);
                }
            }
        }
    }
    for (; e < e1; ++e) {
        int sA = col[e];
        float wA = wcsr[e] * di;
        if (act) {
            bf16x8 vA = *(const bf16x8*)(xb + (long)sA * K1 + c);
#pragma unroll
            for (int j = 0; j < 8; ++j) acc0[j] = fmaf(wA, (float)vA[j], acc0[j]);
        }
    }
    if (act) {
        bf16x8 ob;
#pragma unroll
        for (int j = 0; j < 8; ++j) ob[j] = (bf16_t)(acc0[j] + acc1[j]);
        *reinterpret_cast<bf16x8*>(aggx + (long)i * K1 + c) = ob;
    }
}

// ---------------------------------------------------------------------------
// Fused x1 aggregation (GCN2 weighted sum + SAGE mean); pre-normalized wcsr.
// ---------------------------------------------------------------------------
__global__ __launch_bounds__(256) void agg_x1(
    const bf16_t* __restrict__ x1b /* dense_bf, cols [0,512) */,
    const int* __restrict__ rowptr, const int* __restrict__ col,
    const float* __restrict__ wcsr, const float* __restrict__ dinv,
    const float* __restrict__ deg, const int* __restrict__ cnt,
    bf16_t* __restrict__ gbf, bf16_t* __restrict__ meanb)
{
    int i = blockIdx.x * 4 + (threadIdx.x >> 6);
    int lane = threadIdx.x & 63;
    int c = lane * 8;
    float di = dinv[i];
    float selfw = 1.0f / deg[i];
    bf16x8 sv = *(const bf16x8*)(x1b + (long)i * DENSE_F + c);
    float g0[8], g1[8], m0[8], m1[8];
#pragma unroll
    for (int j = 0; j < 8; ++j) {
        g0[j] = selfw * (float)sv[j];
        g1[j] = 0.f; m0[j] = 0.f; m1[j] = 0.f;
    }
    int e = rowptr[i], e1 = rowptr[i + 1];
    for (; e + 7 < e1; e += 8) {
        int ss[8]; float ww[8];
#pragma unroll
        for (int q = 0; q < 8; ++q) ss[q] = col[e + q];
#pragma unroll
        for (int q = 0; q < 8; ++q) ww[q] = wcsr[e + q] * di;
        bf16x8 vv[8];
#pragma unroll
        for (int q = 0; q < 8; ++q)
            vv[q] = *(const bf16x8*)(x1b + (long)ss[q] * DENSE_F + c);
#pragma unroll
        for (int q = 0; q < 8; ++q) {
#pragma unroll
            for (int j = 0; j < 8; ++j) {
                float f = (float)vv[q][j];
                if (q & 1) { g1[j] = fmaf(ww[q], f, g1[j]); m1[j] += f; }
                else       { g0[j] = fmaf(ww[q], f, g0[j]); m0[j] += f; }
            }
        }
    }
    for (; e < e1; ++e) {
        int sA = col[e];
        float wA = wcsr[e] * di;
        bf16x8 vA = *(const bf16x8*)(x1b + (long)sA * DENSE_F + c);
#pragma unroll
        for (int j = 0; j < 8; ++j) {
            float fA = (float)vA[j];
            g0[j] = fmaf(wA, fA, g0[j]);
            m0[j] += fA;
        }
    }
    float inv = 1.0f / fmaxf((float)cnt[i], 1.0f);
    bf16x8 og, om;
#pragma unroll
    for (int j = 0; j < 8; ++j) {
        og[j] = (bf16_t)(g0[j] + g1[j]);
        om[j] = (bf16_t)((m0[j] + m1[j]) * inv);
    }
    *reinterpret_cast<bf16x8*>(gbf   + (long)i * HID + c) = og;
    *reinterpret_cast<bf16x8*>(meanb + (long)i * HID + c) = om;
}

// ---------------------------------------------------------------------------
// per-dst GAT attention over CSR (+self loop), softmax shift-free.
// 32 lanes per node, 2 nodes/wave, 8/block, 8-edge unroll. (R6-verified.)
// ---------------------------------------------------------------------------
__global__ __launch_bounds__(256) void gat_agg(
    const float* __restrict__ hgat, const int* __restrict__ rowptr,
    const int* __restrict__ col, const float* __restrict__ asrc,
    const float* __restrict__ adst, const float* __restrict__ b1p,
    const float* __restrict__ b2p, float* __restrict__ xout)
{
    int i = blockIdx.x * 8 + (threadIdx.x >> 5);
    int l32 = threadIdx.x & 31;
    int h = (l32 < NHEADS) ? l32 : 0;
    float hg_i = hgat[(long)i * HG_LD + h];
    float as = asrc[h], ad = adst[h];
    float adhg = ad * hg_i;
    float ev = hg_i * as + adhg;
    ev = ev > 0.f ? ev : 0.2f * ev;
    float ex = __expf(ev);
    float den0 = ex, og0 = ex * hg_i, den1 = 0.f, og1 = 0.f;
    int e = rowptr[i], e1 = rowptr[i + 1];
    for (; e + 7 < e1; e += 8) {
        int ss[8];
#pragma unroll
        for (int q = 0; q < 8; ++q) ss[q] = col[e + q];
        float hh[8];
#pragma unroll
        for (int q = 0; q < 8; ++q) hh[q] = hgat[(long)ss[q] * HG_LD + h];
#pragma unroll
        for (int q = 0; q < 8; ++q) {
            float t = fmaf(hh[q], as, adhg); t = t > 0.f ? t : 0.2f * t;
            float xq = __expf(t);
            if (q & 1) { den1 += xq; og1 = fmaf(xq, hh[q], og1); }
            else       { den0 += xq; og0 = fmaf(xq, hh[q], og0); }
        }
    }
    for (; e < e1; ++e) {
        int sA = col[e];
        float hA = hgat[(long)sA * HG_LD + h];
        float tA = fmaf(hA, as, adhg); tA = tA > 0.f ? tA : 0.2f * tA;
        float xA = __expf(tA);
        den0 += xA; og0 = fmaf(xA, hA, og0);
    }
    float out = (l32 < NHEADS) ? (og0 + og1) / (den0 + den1) : 0.f;
    float s4 = out + __shfl_xor(out, 1);
    s4 += __shfl_xor(s4, 2);
    int base = (threadIdx.x & 63) & 32;   // wave-lane base of this node's group
    float g0 = __shfl(s4, base + 0);
    float g1 = __shfl(s4, base + 4);
    float g2 = __shfl(s4, base + 8);
    float g3 = __shfl(s4, base + 12);
    float g4 = __shfl(s4, base + 16);
    if (l32 == 0) {
        float a1 = g0 * 0.25f + b1p[0];
        float a2 = (g1 + g2 + g3 + g4) * 0.0625f + b2p[0];
        xout[i] = 0.5f * (a1 + a2);
    }
}

// ---------------------------------------------------------------------------
extern "C" void kernel_launch(void* const* d_in, const int* in_sizes, int n_in,
                              void* d_out, int out_size, void* d_ws, size_t ws_size,
                              hipStream_t stream) {
    (void)in_sizes; (void)n_in; (void)out_size; (void)ws_size;
    const float* x    = (const float*)d_in[0];
    const int*   ei   = (const int*)d_in[1];
    const float* ew   = (const float*)d_in[2];
    const float* W1   = (const float*)d_in[3];
    const float* b1   = (const float*)d_in[4];
    const float* W2   = (const float*)d_in[5];
    const float* b2   = (const float*)d_in[6];
    const float* sWl  = (const float*)d_in[7];
    const float* sWr  = (const float*)d_in[8];
    const float* sb   = (const float*)d_in[9];
    const float* g1W  = (const float*)d_in[10];
    const float* g1as = (const float*)d_in[11];
    const float* g1ad = (const float*)d_in[12];
    const float* g1b  = (const float*)d_in[13];
    const float* g2W  = (const float*)d_in[14];
    const float* g2as = (const float*)d_in[15];
    const float* g2ad = (const float*)d_in[16];
    const float* g2b  = (const float*)d_in[17];

    const int* src = ei;
    const int* dst = ei + N_EDGES;

    float* xout  = (float*)d_out;          // [N]
    float* dense = xout + N_NODES;         // [N,1536] fp32 (output 2)

    size_t off = 0;
    auto alloc = [&](size_t nbytes) -> void* {
        void* p = (char*)d_ws + off;
        off += (nbytes + 255) & ~(size_t)255;
        return p;
    };
    bf16_t* dense_bf = (bf16_t*)alloc((size_t)M_PAD * DENSE_F * 2);
    bf16_t* x_bf     = (bf16_t*)alloc((size_t)M_PAD * K1 * 2);
    bf16_t* aggx_bf  = (bf16_t*)alloc((size_t)M_PAD * K1 * 2);
    bf16_t* g_bf     = (bf16_t*)alloc((size_t)M_PAD * HID * 2);
    bf16_t* mean_bf  = (bf16_t*)alloc((size_t)M_PAD * HID * 2);
    float*  hgat     = (float*)alloc((size_t)M_PAD * HG_LD * 4);
    bf16_t* W1t      = (bf16_t*)alloc((size_t)512 * K1 * 2);
    bf16_t* W2t      = (bf16_t*)alloc((size_t)512 * 512 * 2);
    bf16_t* Bst      = (bf16_t*)alloc((size_t)512 * 1024 * 2);
    bf16_t* Wgt      = (bf16_t*)alloc((size_t)128 * DENSE_F * 2);
    float*  deg      = (float*)alloc((size_t)N_NODES * 4);   // adjacent to cnt:
    int*    cnt      = (int*)alloc((size_t)N_NODES * 4);     // one fused memset
    float*  dinv     = (float*)alloc((size_t)N_NODES * 4);
    float*  asrc     = (float*)alloc(32 * 4);
    float*  adst     = (float*)alloc(32 * 4);
    int*    rowp     = (int*)alloc((size_t)(N_NODES + 1) * 4);
    int*    woff     = (int*)alloc((size_t)N_NODES * 4);
    int*    colx     = (int*)alloc((size_t)N_EDGES * 4);
    float*  wcsr     = (float*)alloc((size_t)N_EDGES * 4);

    const int EB = EB_BLOCKS;

    // deg (padded to 120064) + cnt are contiguous: single fused memset
    hipMemsetAsync(deg, 0, (size_t)((char*)cnt - (char*)deg) + N_NODES * 4, stream);

    // Fused: build_stats || conv_x (float4) || pack_weights
    prologue<<<PRO_BLOCKS, 256, 0, stream>>>(
        dst, ew, deg, cnt, x, x_bf,
        W1, W2, sWl, sWr, g1W, g2W, g1as, g1ad, g2as, g2ad,
        W1t, W2t, Bst, Wgt, asrc, adst);
    // Fused: exclusive scan + node_stats (deg+1, rsqrt)
    scan_rowptr_fast<<<1, 1024, 0, stream>>>(cnt, rowp, woff, deg, dinv);
    // CSR scatter with dinv[src] folded into wcsr
    scatter_csr<<<EB, 256, 0, stream>>>(src, dst, ew, dinv, woff, colx, wcsr);

    const dim3 gB(256);
    const int NT = M_PAD / 128;                   // 235 row tiles

    // GCN1 (commuted): aggx = A_gcn * x ; x1 = relu(aggx@W1 + b1) -> dense[:,0:512]
    agg_x<<<N_NODES / 4, 256, 0, stream>>>(x_bf, rowp, colx, wcsr, dinv, deg, aggx_bf);
    gemm_bf16<<<4 * NT, gB, 0, stream>>>(aggx_bf, K1, K1, aggx_bf, K1, W1t, K1,
                                         dense, dense_bf, DENSE_F, K1, b1, 512, 4);

    // Fused x1 gather: g = A_gcn * x1 (GCN2), mean = mean(x1) (SAGE)
    agg_x1<<<N_NODES / 4, 256, 0, stream>>>(dense_bf, rowp, colx, wcsr, dinv, deg, cnt,
                                            g_bf, mean_bf);
    // GCN2 + SAGE fused into one launch (independent GEMMs):
    //   x2 = relu(g@W2 + b2)                 -> dense[:,512:1024]
    //   x3 = relu([mean|x1]@[Wl;Wr] + sb)    -> dense[:,1024:1536]
    gemm_bf16_dual<<<8 * NT, gB, 0, stream>>>(
        g_bf, HID, HID, g_bf, HID, W2t, HID,
        dense + HID, dense_bf + HID, DENSE_F, HID, b2, 512,
        mean_bf, HID, HID, dense_bf, DENSE_F, Bst, 1024,
        dense + 2 * HID, dense_bf + 2 * HID, DENSE_F, 1024, sb, 512);

    // GAT: hgat = dense @ Wg (fp32, masked to 32 cols, stride 32), then aggregate
    gemm_bf16<<<1 * NT, gB, 0, stream>>>(dense_bf, DENSE_F, DENSE_F, dense_bf, DENSE_F,
                                         Wgt, DENSE_F, hgat, nullptr, HG_LD,
                                         DENSE_F, nullptr, HG_LD, 1);
    gat_agg<<<N_NODES / 8, 256, 0, stream>>>(hgat, rowp, colx, asrc, adst, g1b, g2b, xout);
}